// Round 8
// baseline (471.843 us; speedup 1.0000x reference)
//
#include <hip/hip_runtime.h>

// PointNet++-style decoder forward: 3 levels of {knn_interpolate -> concat ->
// Lin+BN+ReLU -> residual Lin+BN+ReLU}. All fp32. Single batch.

#define EPS_BN 1e-5f
#define EPS_W  1e-16f

// ---- L2 KNN spatial grid parameters (sources = 8192 Gaussian pts) ---------
#define GRD    52
#define GLO   -6.5f
#define GH     0.25f
#define GIH    4.0f
#define NCELLS (GRD * GRD * GRD)   // 140608

typedef unsigned long long u64;

// ---------------------------------------------------------------------------
// Brute KNN pass 1 (levels 0,1): split over sources. Block = 256 threads x
// TPT targets vs one source chunk in LDS. Branchless sorted top-3.
// ---------------------------------------------------------------------------
template<int TPT>
__global__ __launch_bounds__(256)
void knn_part(const float* __restrict__ pos_s, const float* __restrict__ pos_t,
              int Ns, int Nt, int nsplit,
              float* __restrict__ cand_d, int* __restrict__ cand_i)
{
  __shared__ float4 sp[512];

  const int tb  = blockIdx.x;
  const int spl = blockIdx.y;
  const int chunk = Ns / nsplit;
  const int cs = spl * chunk;

  float tx[TPT], ty[TPT], tz[TPT];
  float d0[TPT], d1[TPT], d2[TPT];
  int   j0[TPT], j1[TPT], j2[TPT];

#pragma unroll
  for (int q = 0; q < TPT; ++q) {
    int t = tb * 256 * TPT + q * 256 + threadIdx.x;
    tx[q] = pos_t[3 * t + 0];
    ty[q] = pos_t[3 * t + 1];
    tz[q] = pos_t[3 * t + 2];
    d0[q] = 3.4e38f; d1[q] = 3.4e38f; d2[q] = 3.4e38f;
    j0[q] = 0; j1[q] = 0; j2[q] = 0;
  }

  for (int i = threadIdx.x; i < chunk; i += 256) {
    int p = cs + i;
    sp[i] = make_float4(pos_s[3 * p], pos_s[3 * p + 1], pos_s[3 * p + 2], 0.f);
  }
  __syncthreads();

#pragma unroll 4
  for (int j = 0; j < chunk; ++j) {
    float4 s = sp[j];
    int gj = cs + j;
#pragma unroll
    for (int q = 0; q < TPT; ++q) {
      float dx = tx[q] - s.x, dy = ty[q] - s.y, dz = tz[q] - s.z;
      float nd = fmaf(dz, dz, fmaf(dy, dy, dx * dx));
      int nj = gj;
      bool c = nd < d0[q];
      float td = c ? d0[q] : nd;  int tj = c ? j0[q] : nj;
      d0[q] = c ? nd : d0[q];     j0[q] = c ? nj : j0[q];
      nd = td; nj = tj;
      c = nd < d1[q];
      td = c ? d1[q] : nd;        tj = c ? j1[q] : nj;
      d1[q] = c ? nd : d1[q];     j1[q] = c ? nj : j1[q];
      nd = td; nj = tj;
      c = nd < d2[q];
      d2[q] = c ? nd : d2[q];     j2[q] = c ? nj : j2[q];
    }
  }

#pragma unroll
  for (int q = 0; q < TPT; ++q) {
    int t = tb * 256 * TPT + q * 256 + threadIdx.x;
    int o = (t * nsplit + spl) * 3;
    cand_d[o + 0] = d0[q]; cand_d[o + 1] = d1[q]; cand_d[o + 2] = d2[q];
    cand_i[o + 0] = j0[q]; cand_i[o + 1] = j1[q]; cand_i[o + 2] = j2[q];
  }
}

// ---------------------------------------------------------------------------
// Merge + gather (all levels): block = 64 targets x 4 channel-groups.
// FROMW=0: merge nsplit partial top-3 lists; FROMW=1: read widx (L2 path).
// Block 0 zeroes the BN stats accumulators for the following GEMMs.
// ---------------------------------------------------------------------------
template<int CS, int FROMW>
__global__ __launch_bounds__(256)
void merge_gather(const float* __restrict__ cand_d, const int* __restrict__ cand_i,
                  int nsplit, const float* __restrict__ xs,
                  float* __restrict__ up, int Nt,
                  float* __restrict__ stats0, const float* __restrict__ widx)
{
  if (blockIdx.x == 0) {
    for (int i = threadIdx.x; i < 1024; i += 256) stats0[i] = 0.f;
  }

  int t  = blockIdx.x * 64 + (threadIdx.x >> 2);
  int cg = threadIdx.x & 3;

  float w0, w1, w2; int i0, i1, i2;
  if (FROMW) {
    float4 wv = *(const float4*)&widx[(size_t)t * 8];
    float4 iv = *(const float4*)&widx[(size_t)t * 8 + 4];
    w0 = wv.x; w1 = wv.y; w2 = wv.z;
    i0 = (int)__float_as_uint(iv.x);
    i1 = (int)__float_as_uint(iv.y);
    i2 = (int)__float_as_uint(iv.z);
  } else {
    float e0 = 3.5e38f, e1 = 3.5e38f, e2 = 3.5e38f;
    i0 = 0; i1 = 0; i2 = 0;
    int o = t * nsplit * 3;
    for (int c = 0; c < nsplit * 3; ++c) {
      float d = cand_d[o + c];
      int   i = cand_i[o + c];
      if (d < e2) {
        if (d < e1) {
          e2 = e1; i2 = i1;
          if (d < e0) { e1 = e0; i1 = i0; e0 = d; i0 = i; }
          else        { e1 = d;  i1 = i; }
        } else { e2 = d; i2 = i; }
      }
    }
    w0 = 1.f / fmaxf(e0, EPS_W);
    w1 = 1.f / fmaxf(e1, EPS_W);
    w2 = 1.f / fmaxf(e2, EPS_W);
    float inv = 1.f / (w0 + w1 + w2);
    w0 *= inv; w1 *= inv; w2 *= inv;
  }

  const float4* r0 = (const float4*)(xs + (size_t)i0 * CS);
  const float4* r1 = (const float4*)(xs + (size_t)i1 * CS);
  const float4* r2 = (const float4*)(xs + (size_t)i2 * CS);
  float4* ou = (float4*)(up + (size_t)t * CS);
  const int F4 = CS / 4;
#pragma unroll 4
  for (int k = 0; k < F4 / 4; ++k) {
    int f = cg + 4 * k;
    float4 a = r0[f], b = r1[f], d = r2[f], rr;
    rr.x = w0 * a.x + w1 * b.x + w2 * d.x;
    rr.y = w0 * a.y + w1 * b.y + w2 * d.y;
    rr.z = w0 * a.z + w1 * b.z + w2 * d.z;
    rr.w = w0 * a.w + w1 * b.w + w2 * d.w;
    ou[f] = rr;
  }
}

// ---------------------------------------------------------------------------
// Grid build (L2). Fused source/target variants via blockIdx.y.
// ---------------------------------------------------------------------------
__device__ __forceinline__ int cell_coord(float v) {
  return min(max((int)floorf((v - GLO) * GIH), 0), GRD - 1);
}

__global__ __launch_bounds__(256)
void grid_count2(const float* __restrict__ ps, int ns, int* __restrict__ cnt,
                 int* __restrict__ pcell,
                 const float* __restrict__ pt, int nt, int* __restrict__ tcnt,
                 int* __restrict__ tpcell)
{
  int i = blockIdx.x * 256 + threadIdx.x;
  const float* p; int n; int* c; int* pc;
  if (blockIdx.y == 0) { p = ps; n = ns; c = cnt;  pc = pcell; }
  else                 { p = pt; n = nt; c = tcnt; pc = tpcell; }
  if (i >= n) return;
  int cx = cell_coord(p[3 * i + 0]);
  int cy = cell_coord(p[3 * i + 1]);
  int cz = cell_coord(p[3 * i + 2]);
  int cid = (cz * GRD + cy) * GRD + cx;
  pc[i] = cid;
  atomicAdd(&c[cid], 1);
}

__global__ __launch_bounds__(256)
void grid_scan1(const int* __restrict__ cntA, int* __restrict__ ofspA,
                int* __restrict__ auxA,
                const int* __restrict__ cntB, int* __restrict__ ofspB,
                int* __restrict__ auxB)
{
  const int* cnt; int* ofsp; int* aux;
  if (blockIdx.y == 0) { cnt = cntA; ofsp = ofspA; aux = auxA; }
  else                 { cnt = cntB; ofsp = ofspB; aux = auxB; }
  __shared__ int arr[256];
  int tid = threadIdx.x;
  int c0 = blockIdx.x * 1024 + tid * 4;
  int s0 = (c0 + 0 < NCELLS) ? cnt[c0 + 0] : 0;
  int s1 = (c0 + 1 < NCELLS) ? cnt[c0 + 1] : 0;
  int s2 = (c0 + 2 < NCELLS) ? cnt[c0 + 2] : 0;
  int s3 = (c0 + 3 < NCELLS) ? cnt[c0 + 3] : 0;
  int p1 = s0, p2 = s0 + s1, p3 = p2 + s2, tot = p3 + s3;
  arr[tid] = tot; __syncthreads();
  for (int d = 1; d < 256; d <<= 1) {
    int v = (tid >= d) ? arr[tid - d] : 0;
    __syncthreads();
    arr[tid] += v;
    __syncthreads();
  }
  int excl = arr[tid] - tot;
  if (c0 + 0 < NCELLS) ofsp[c0 + 0] = excl;
  if (c0 + 1 < NCELLS) ofsp[c0 + 1] = excl + p1;
  if (c0 + 2 < NCELLS) ofsp[c0 + 2] = excl + p2;
  if (c0 + 3 < NCELLS) ofsp[c0 + 3] = excl + p3;
  if (tid == 255) aux[blockIdx.x] = arr[255];
}

__global__ __launch_bounds__(256)
void grid_scan2(const int* __restrict__ auxA, int* __restrict__ auxpA,
                const int* __restrict__ auxB, int* __restrict__ auxpB, int nblk)
{
  const int* aux; int* auxp;
  if (blockIdx.x == 0) { aux = auxA; auxp = auxpA; }
  else                 { aux = auxB; auxp = auxpB; }
  __shared__ int arr[256];
  int tid = threadIdx.x;
  int v = (tid < nblk) ? aux[tid] : 0;
  arr[tid] = v; __syncthreads();
  for (int d = 1; d < 256; d <<= 1) {
    int w = (tid >= d) ? arr[tid - d] : 0;
    __syncthreads();
    arr[tid] += w;
    __syncthreads();
  }
  auxp[tid] = arr[tid] - v;   // exclusive
}

// side 0: cursor + cellstart (+sentinel, ovfc=0); side 1: tcursor only.
__global__ __launch_bounds__(256)
void grid_fixup2(const int* __restrict__ ofsp, const int* __restrict__ auxp,
                 int* __restrict__ cursor, int* __restrict__ cellstart,
                 int ns_total,
                 const int* __restrict__ tofsp, const int* __restrict__ tauxp,
                 int* __restrict__ tcursor, int* __restrict__ ovf_cnt)
{
  int i = blockIdx.x * 256 + threadIdx.x;
  if (blockIdx.y == 0) {
    if (i == 0) { *ovf_cnt = 0; cellstart[NCELLS] = ns_total; }
    for (int c = i; c < NCELLS; c += gridDim.x * 256) {
      int v = ofsp[c] + auxp[c >> 10];
      cursor[c] = v;
      cellstart[c] = v;
    }
  } else {
    for (int c = i; c < NCELLS; c += gridDim.x * 256)
      tcursor[c] = tofsp[c] + tauxp[c >> 10];
  }
}

// side 0: scatter source points as float4(pos,idx); side 1: target index sort.
__global__ __launch_bounds__(256)
void grid_scatter2(const float* __restrict__ ps, int ns,
                   const int* __restrict__ pcell, int* __restrict__ cursor,
                   float4* __restrict__ plist,
                   int nt, const int* __restrict__ tpcell,
                   int* __restrict__ tcursor, int* __restrict__ tsorted)
{
  int i = blockIdx.x * 256 + threadIdx.x;
  if (blockIdx.y == 0) {
    if (i >= ns) return;
    int slot = atomicAdd(&cursor[pcell[i]], 1);
    plist[slot] = make_float4(ps[3 * i], ps[3 * i + 1], ps[3 * i + 2],
                              __uint_as_float((unsigned)i));
  } else {
    if (i >= nt) return;
    int slot = atomicAdd(&tcursor[tpcell[i]], 1);
    tsorted[slot] = i;
  }
}

// ---------------------------------------------------------------------------
// L2 KNN search, quad-per-target: 4 lanes share one target; phase-1 rows
// (9 contiguous x-row ranges) and phase-2 ranges (34) are split across the
// quad and merged with a 2-round shfl_xor butterfly (disjoint sets only).
// u64 keys (dist<<32|idx): scatter-order independent, ties by smaller index.
// Certify via exact cube-face lower bound at r=1,2; else overflow -> brute.
// ---------------------------------------------------------------------------
__device__ __forceinline__ void key_insert(u64 nk, u64& k0, u64& k1, u64& k2) {
  bool c = nk < k0; u64 tk = c ? k0 : nk; k0 = c ? nk : k0; nk = tk;
  c = nk < k1; tk = c ? k1 : nk; k1 = c ? nk : k1; nk = tk;
  c = nk < k2; k2 = c ? nk : k2;
}

__device__ __forceinline__ void quad_merge(u64& k0, u64& k1, u64& k2) {
#pragma unroll
  for (int off = 1; off <= 2; off <<= 1) {
    u64 a0 = __shfl_xor(k0, off);
    u64 a1 = __shfl_xor(k1, off);
    u64 a2 = __shfl_xor(k2, off);
    key_insert(a0, k0, k1, k2);
    key_insert(a1, k0, k1, k2);
    key_insert(a2, k0, k1, k2);
  }
}

__global__ __launch_bounds__(256)
void knn_search_quad(const float* __restrict__ pos_t, int Nt,
                     const int* __restrict__ cellstart,
                     const float4* __restrict__ plist,
                     const int* __restrict__ tsorted,
                     float* __restrict__ widx,
                     int* __restrict__ ovf_cnt, int* __restrict__ ovf)
{
  int gid = blockIdx.x * 64 + (threadIdx.x >> 2);   // 64 targets per block
  int sub = threadIdx.x & 3;
  if (gid >= Nt) return;
  int t = tsorted[gid];
  float tx = pos_t[3 * t], ty = pos_t[3 * t + 1], tz = pos_t[3 * t + 2];
  int cx = cell_coord(tx), cy = cell_coord(ty), cz = cell_coord(tz);

  u64 k0 = ~0ULL, k1 = ~0ULL, k2 = ~0ULL;

  auto scan_range = [&](int p0, int p1, u64& a0, u64& a1, u64& a2) {
    for (int p = p0; p < p1; ++p) {
      float4 s = plist[p];
      float dx = tx - s.x, dy = ty - s.y, dz = tz - s.z;
      float d = fmaf(dz, dz, fmaf(dy, dy, dx * dx));
      key_insert(((u64)__float_as_uint(d) << 32) | (u64)__float_as_uint(s.w),
                 a0, a1, a2);
    }
  };

  auto certify = [&](int R) -> bool {
    int xl = max(cx - R, 0), xh = min(cx + R, GRD - 1);
    int yl = max(cy - R, 0), yh = min(cy + R, GRD - 1);
    int zl = max(cz - R, 0), zh = min(cz + R, GRD - 1);
    float m = 1e30f;
    if (xl > 0)       m = fminf(m, tx - (GLO + xl * GH));
    if (xh < GRD - 1) m = fminf(m, (GLO + (xh + 1) * GH) - tx);
    if (yl > 0)       m = fminf(m, ty - (GLO + yl * GH));
    if (yh < GRD - 1) m = fminf(m, (GLO + (yh + 1) * GH) - ty);
    if (zl > 0)       m = fminf(m, tz - (GLO + zl * GH));
    if (zh < GRD - 1) m = fminf(m, (GLO + (zh + 1) * GH) - tz);
    float d2b = __uint_as_float((unsigned)(k2 >> 32));   // NaN if <3 found
    return (m * m * 0.9999f > d2b);                      // NaN -> false
  };

  // Phase 1: 9 rows split across the quad (lane sub: rows sub, sub+4, sub+8)
  int xlo = max(cx - 1, 0), xhi = min(cx + 1, GRD - 1);
  for (int id = sub; id < 9; id += 4) {
    int y = cy + (id % 3) - 1, z = cz + (id / 3) - 1;
    if (((unsigned)y < GRD) && ((unsigned)z < GRD)) {
      int base = (z * GRD + y) * GRD;
      scan_range(cellstart[base + xlo], cellstart[base + xhi + 1], k0, k1, k2);
    }
  }
  quad_merge(k0, k1, k2);          // disjoint partials -> all lanes hold top-3
  bool done = certify(1);

  if (!done) {
    // Phase 2: r=2 shell as 34 ranges: 16 outer rows (full x span) +
    // 9 inner rows x 2 caps. Fresh keys per lane (disjoint), butterfly,
    // then one cross-set merge into the shared phase-1 keys.
    static const signed char o_dy[16] = {-2,-1,0,1,2, -2,-1,0,1,2, -2,-2,-2, 2,2,2};
    static const signed char o_dz[16] = {-2,-2,-2,-2,-2, 2,2,2,2,2, -1,0,1, -1,0,1};
    int xl2 = max(cx - 2, 0), xh2 = min(cx + 2, GRD - 1);
    u64 p0 = ~0ULL, p1 = ~0ULL, p2 = ~0ULL;
    for (int id = sub; id < 34; id += 4) {
      if (id < 16) {
        int y = cy + o_dy[id], z = cz + o_dz[id];
        if (((unsigned)y < GRD) && ((unsigned)z < GRD)) {
          int base = (z * GRD + y) * GRD;
          scan_range(cellstart[base + xl2], cellstart[base + xh2 + 1], p0, p1, p2);
        }
      } else {
        int row = (id - 16) >> 1, side = (id - 16) & 1;
        int y = cy + (row % 3) - 1, z = cz + (row / 3) - 1;
        int x = side ? (cx + 2) : (cx - 2);
        if (((unsigned)y < GRD) && ((unsigned)z < GRD) && ((unsigned)x < GRD)) {
          int base = (z * GRD + y) * GRD;
          scan_range(cellstart[base + x], cellstart[base + x + 1], p0, p1, p2);
        }
      }
    }
    quad_merge(p0, p1, p2);
    key_insert(p0, k0, k1, k2);    // phase-2 set disjoint from phase-1 set
    key_insert(p1, k0, k1, k2);
    key_insert(p2, k0, k1, k2);
    done = certify(2);
  }

  if (!done) {
    if (sub == 0) ovf[atomicAdd(ovf_cnt, 1)] = t;
    return;
  }

  if (sub == 0) {
    float d0 = __uint_as_float((unsigned)(k0 >> 32));
    float d1 = __uint_as_float((unsigned)(k1 >> 32));
    float d2 = __uint_as_float((unsigned)(k2 >> 32));
    float w0 = 1.f / fmaxf(d0, EPS_W);
    float w1 = 1.f / fmaxf(d1, EPS_W);
    float w2 = 1.f / fmaxf(d2, EPS_W);
    float inv = 1.f / (w0 + w1 + w2);
    *(float4*)&widx[(size_t)t * 8] =
        make_float4(w0 * inv, w1 * inv, w2 * inv, 0.f);
    *(float4*)&widx[(size_t)t * 8 + 4] =
        make_float4(__uint_as_float((unsigned)k0), __uint_as_float((unsigned)k1),
                    __uint_as_float((unsigned)k2), 0.f);
  }
}

// ---------------------------------------------------------------------------
// Brute fallback: 4 targets/block (one per wave), sources staged through LDS
// in 1024-point tiles; wave-tree shfl merge. Exact u64 keys.
// ---------------------------------------------------------------------------
__global__ __launch_bounds__(256)
void knn_brute(const float* __restrict__ pos_t, const float4* __restrict__ plist,
               int Ns, const int* __restrict__ ovf_cnt,
               const int* __restrict__ ovf, float* __restrict__ widx)
{
  __shared__ float4 tile[1024];
  int n = *ovf_cnt;
  int ngrp = (n + 3) >> 2;                       // 4 targets per block
  int wv = threadIdx.x >> 6, ln = threadIdx.x & 63;

  for (int g = blockIdx.x; g < ngrp; g += gridDim.x) {
    int o = g * 4 + wv;
    bool active = (o < n);
    int t = active ? ovf[o] : 0;
    float tx = pos_t[3 * t], ty = pos_t[3 * t + 1], tz = pos_t[3 * t + 2];
    u64 k0 = ~0ULL, k1 = ~0ULL, k2 = ~0ULL;

    for (int base = 0; base < Ns; base += 1024) {
      int m = min(1024, Ns - base);
      __syncthreads();
      for (int i = threadIdx.x; i < m; i += 256) tile[i] = plist[base + i];
      __syncthreads();
#pragma unroll 4
      for (int p = ln; p < m; p += 64) {
        float4 s = tile[p];
        float dx = tx - s.x, dy = ty - s.y, dz = tz - s.z;
        float d = fmaf(dz, dz, fmaf(dy, dy, dx * dx));
        key_insert(((u64)__float_as_uint(d) << 32) | (u64)__float_as_uint(s.w),
                   k0, k1, k2);
      }
    }

    // wave tree-merge: after 6 rounds lane 0 holds the global top-3
#pragma unroll
    for (int off = 32; off >= 1; off >>= 1) {
      u64 a0 = __shfl_down(k0, off);
      u64 a1 = __shfl_down(k1, off);
      u64 a2 = __shfl_down(k2, off);
      key_insert(a0, k0, k1, k2);
      key_insert(a1, k0, k1, k2);
      key_insert(a2, k0, k1, k2);
    }

    if (active && ln == 0) {
      float d0 = __uint_as_float((unsigned)(k0 >> 32));
      float d1 = __uint_as_float((unsigned)(k1 >> 32));
      float d2 = __uint_as_float((unsigned)(k2 >> 32));
      float w0 = 1.f / fmaxf(d0, EPS_W);
      float w1 = 1.f / fmaxf(d1, EPS_W);
      float w2 = 1.f / fmaxf(d2, EPS_W);
      float inv = 1.f / (w0 + w1 + w2);
      *(float4*)&widx[(size_t)t * 8] =
          make_float4(w0 * inv, w1 * inv, w2 * inv, 0.f);
      *(float4*)&widx[(size_t)t * 8 + 4] =
          make_float4(__uint_as_float((unsigned)k0), __uint_as_float((unsigned)k1),
                      __uint_as_float((unsigned)k2), 0.f);
    }
  }
}

// ---------------------------------------------------------------------------
// fp32 tiled GEMM v2: Z[m][n] = sum_k A[m][k]*B[n][k] + bias[n].
// Conflict-free LDS (A row-major [BM][BK+4] float4 writes + broadcast reads;
// B [BK][BN+1] pad-1), register prefetch (issue-early/write-late), high
// occupancy (BM=32 tiles -> 512-1024 blocks, launch_bounds(256,4)).
// CONCAT: A = [A0 (C0 cols) | A1]; BNIN: A = relu(bn(A0)).
// Epilogue: fused per-column sum/sumsq for the next BatchNorm.
// ---------------------------------------------------------------------------
template<int BM, int BN, int CONCAT, int BNIN>
__global__ __launch_bounds__(256, 4)
void gemm_k(const float* __restrict__ A0, const float* __restrict__ A1, int C0,
            const float* __restrict__ B, const float* __restrict__ bias,
            const float* __restrict__ s_in, const float* __restrict__ q_in,
            const float* __restrict__ g_in, const float* __restrict__ be_in,
            float* __restrict__ Z, float* __restrict__ s_out, float* __restrict__ q_out,
            int M, int K, int N)
{
  const int BK = 32;
  const int TN = BN / 4;          // column-group threads (8 or 16)
  const int TM = 256 / TN;        // row threads (32 or 16)
  const int AR = BM / TM;         // rows per thread
  const int NA = BM / 32;         // A float4 loads per thread
  const int NB = BN / 32;         // B float4 loads per thread

  __shared__ alignas(16) float a_lds[BM][BK + 4];
  __shared__ float b_lds[BK][BN + 1];
  __shared__ float bn_sc[256], bn_sh[256];

  const int tid = threadIdx.x;
  const int tn = tid % TN, tm = tid / TN;
  const int mb = blockIdx.x * BM;
  const int nb = blockIdx.y * BN;

  if (BNIN) {
    for (int c = tid; c < K; c += 256) {
      float mean = s_in[c] / (float)M;
      float var  = q_in[c] / (float)M - mean * mean;
      float rstd = rsqrtf(var + EPS_BN);
      float sc = g_in[c] * rstd;
      bn_sc[c] = sc;
      bn_sh[c] = be_in[c] - mean * sc;
    }
    __syncthreads();
  }

  float acc[AR][4];
#pragma unroll
  for (int i = 0; i < AR; ++i)
#pragma unroll
    for (int j = 0; j < 4; ++j) acc[i][j] = 0.f;

  float4 pa[NA], pb[NB];

  auto prefetch = [&](int kb) {
    const float* Ap; int ldA, ko;
    if (CONCAT) {
      if (kb < C0) { Ap = A0; ldA = C0;     ko = kb; }
      else         { Ap = A1; ldA = K - C0; ko = kb - C0; }
    } else { Ap = A0; ldA = K; ko = kb; }
#pragma unroll
    for (int i = 0; i < NA; ++i) {
      int sl = tid + 256 * i;
      int m = sl >> 3, k4 = (sl & 7) * 4;
      pa[i] = *(const float4*)(Ap + (size_t)(mb + m) * ldA + ko + k4);
    }
#pragma unroll
    for (int i = 0; i < NB; ++i) {
      int sl = tid + 256 * i;
      int nn = sl >> 3, k4 = (sl & 7) * 4;
      pb[i] = *(const float4*)(B + (size_t)(nb + nn) * K + kb + k4);
    }
  };

  prefetch(0);

  for (int kb = 0; kb < K; kb += BK) {
    // commit staged registers to LDS
#pragma unroll
    for (int i = 0; i < NA; ++i) {
      int sl = tid + 256 * i;
      int m = sl >> 3, k4 = (sl & 7) * 4;
      float4 v = pa[i];
      if (BNIN) {
        v.x = fmaxf(v.x * bn_sc[kb + k4 + 0] + bn_sh[kb + k4 + 0], 0.f);
        v.y = fmaxf(v.y * bn_sc[kb + k4 + 1] + bn_sh[kb + k4 + 1], 0.f);
        v.z = fmaxf(v.z * bn_sc[kb + k4 + 2] + bn_sh[kb + k4 + 2], 0.f);
        v.w = fmaxf(v.w * bn_sc[kb + k4 + 3] + bn_sh[kb + k4 + 3], 0.f);
      }
      *(float4*)&a_lds[m][k4] = v;
    }
#pragma unroll
    for (int i = 0; i < NB; ++i) {
      int sl = tid + 256 * i;
      int nn = sl >> 3, k4 = (sl & 7) * 4;
      float4 v = pb[i];
      b_lds[k4 + 0][nn] = v.x; b_lds[k4 + 1][nn] = v.y;
      b_lds[k4 + 2][nn] = v.z; b_lds[k4 + 3][nn] = v.w;
    }
    __syncthreads();
    if (kb + BK < K) prefetch(kb + BK);   // overlap with compute below

#pragma unroll
    for (int k = 0; k < BK; ++k) {
      float bv0 = b_lds[k][tn * 4 + 0];
      float bv1 = b_lds[k][tn * 4 + 1];
      float bv2 = b_lds[k][tn * 4 + 2];
      float bv3 = b_lds[k][tn * 4 + 3];
#pragma unroll
      for (int i = 0; i < AR; ++i) {
        float a = a_lds[tm * AR + i][k];
        acc[i][0] = fmaf(a, bv0, acc[i][0]);
        acc[i][1] = fmaf(a, bv1, acc[i][1]);
        acc[i][2] = fmaf(a, bv2, acc[i][2]);
        acc[i][3] = fmaf(a, bv3, acc[i][3]);
      }
    }
    __syncthreads();
  }

  // epilogue: bias add, store, per-column partial stats
  float4 bb = *(const float4*)&bias[nb + tn * 4];
  float psum[4] = {0, 0, 0, 0}, psq[4] = {0, 0, 0, 0};
#pragma unroll
  for (int i = 0; i < AR; ++i) {
    int m = tm * AR + i;
    float4 v;
    v.x = acc[i][0] + bb.x; v.y = acc[i][1] + bb.y;
    v.z = acc[i][2] + bb.z; v.w = acc[i][3] + bb.w;
    *(float4*)(Z + (size_t)(mb + m) * N + nb + tn * 4) = v;
    psum[0] += v.x; psum[1] += v.y; psum[2] += v.z; psum[3] += v.w;
    psq[0] += v.x * v.x; psq[1] += v.y * v.y;
    psq[2] += v.z * v.z; psq[3] += v.w * v.w;
  }
  __syncthreads();
  float* red_s = &b_lds[0][0];   // BK*(BN+1) >= BN*TM = 1024
  float* red_q = &a_lds[0][0];   // BM*(BK+4) >= 1024
#pragma unroll
  for (int j = 0; j < 4; ++j) {
    int c = tn * 4 + j;
    red_s[c * TM + tm] = psum[j];
    red_q[c * TM + tm] = psq[j];
  }
  __syncthreads();
  if (tid < BN) {
    float s = 0.f, q = 0.f;
#pragma unroll
    for (int it = 0; it < TM; ++it) {
      s += red_s[tid * TM + it];
      q += red_q[tid * TM + it];
    }
    atomicAdd(&s_out[nb + tid], s);
    atomicAdd(&q_out[nb + tid], q);
  }
}

// ---------------------------------------------------------------------------
// Final elementwise per level: out = relu(bn1(z1)) + relu(bn2(z2))
// ---------------------------------------------------------------------------
__global__ __launch_bounds__(256)
void final_k(const float* __restrict__ z1, const float* __restrict__ z2,
             const float* __restrict__ s1, const float* __restrict__ q1,
             const float* __restrict__ g1, const float* __restrict__ be1,
             const float* __restrict__ s2, const float* __restrict__ q2,
             const float* __restrict__ g2, const float* __restrict__ be2,
             float* __restrict__ outp, int M, int C)
{
  __shared__ float sc1[256], sh1[256], sc2[256], sh2[256];
  for (int c = threadIdx.x; c < C; c += 256) {
    float mean = s1[c] / (float)M;
    float var  = q1[c] / (float)M - mean * mean;
    float r = rsqrtf(var + EPS_BN);
    sc1[c] = g1[c] * r; sh1[c] = be1[c] - mean * sc1[c];
    mean = s2[c] / (float)M;
    var  = q2[c] / (float)M - mean * mean;
    r = rsqrtf(var + EPS_BN);
    sc2[c] = g2[c] * r; sh2[c] = be2[c] - mean * sc2[c];
  }
  __syncthreads();

  int total4 = M * C / 4;
  int cmask = (C / 4) - 1;                   // C/4 is a power of two
  for (int i = blockIdx.x * 256 + threadIdx.x; i < total4; i += gridDim.x * 256) {
    int c = (i & cmask) * 4;
    float4 a = ((const float4*)z1)[i];
    float4 b = ((const float4*)z2)[i];
    float4 r;
    r.x = fmaxf(a.x * sc1[c + 0] + sh1[c + 0], 0.f) + fmaxf(b.x * sc2[c + 0] + sh2[c + 0], 0.f);
    r.y = fmaxf(a.y * sc1[c + 1] + sh1[c + 1], 0.f) + fmaxf(b.y * sc2[c + 1] + sh2[c + 1], 0.f);
    r.z = fmaxf(a.z * sc1[c + 2] + sh1[c + 2], 0.f) + fmaxf(b.z * sc2[c + 2] + sh2[c + 2], 0.f);
    r.w = fmaxf(a.w * sc1[c + 3] + sh1[c + 3], 0.f) + fmaxf(b.w * sc2[c + 3] + sh2[c + 3], 0.f);
    ((float4*)outp)[i] = r;
  }
}

// ---------------------------------------------------------------------------
extern "C" void kernel_launch(void* const* d_in, const int* in_sizes, int n_in,
                              void* d_out, int out_size, void* d_ws, size_t ws_size,
                              hipStream_t stream)
{
  const bool dict_order = (in_sizes[1] == 512 * 512);

  const float* POS[4];
  const float* X[4];
  for (int i = 0; i < 4; ++i) {
    POS[i] = (const float*)d_in[dict_order ? 3 * i : i];
    X[i]   = (const float*)d_in[dict_order ? 3 * i + 1 : 4 + i];
  }
  static const int dict_map[8] = {0, 2, 6, 3, 1, 4, 7, 5};
  auto PRM = [&](int lvl, int which) -> const float* {
    int idx = dict_order ? (12 + 8 * lvl + dict_map[which]) : (8 + 8 * lvl + which);
    return (const float*)d_in[idx];
  };

  // Workspace layout. cd/ci alias z1/z2 (L0/L1 path); L2 grid scratch also
  // lives in the z1 region (dead before L2 gemm1 writes z1; only widx, which
  // lives outside, survives). Stream order serializes all hazards.
  char* ws = (char*)d_ws;
  float* up    = (float*)(ws);                          // 16 MB max (L2)
  float* z1    = (float*)(ws + (16u << 20));            // 8 MB max
  float* z2    = (float*)(ws + (24u << 20));            // 8 MB max
  float* cd    = z1;
  int*   ci    = (int*)z2;
  float* x1o   = (float*)(ws + (32u << 20));            // 2 MB
  float* x2o   = (float*)(ws + (34u << 20));            // 4 MB
  float* stats = (float*)(ws + (38u << 20));            // 4 KB (pad 8 KB)
  float* s1 = stats, *q1 = stats + 256, *s2 = stats + 512, *q2 = stats + 768;
  float* widx  = (float*)(ws + (38u << 20) + 8192);     // 1 MB

  // grid scratch inside z1 region (<= 5.2 MB of 8 MB)
  char* gb = ws + (16u << 20);
  const size_t S = 600 * 1024;
  int*    cnt      = (int*)(gb + 0 * S);
  int*    tcnt     = (int*)(gb + 1 * S);
  int*    ofsp     = (int*)(gb + 2 * S);
  int*    tofsp    = (int*)(gb + 3 * S);
  int*    cursor   = (int*)(gb + 4 * S);
  int*    tcursor  = (int*)(gb + 5 * S);
  int*    cellstart= (int*)(gb + 6 * S);                // NCELLS+1 ints
  char*   gb2      = gb + 7 * S;
  int*    aux      = (int*)(gb2);
  int*    auxp     = (int*)(gb2 + 1024);
  int*    aux2     = (int*)(gb2 + 2048);
  int*    auxp2    = (int*)(gb2 + 3072);
  int*    pcell    = (int*)(gb2 + 4096);                        // 32 KB
  int*    tpcell   = (int*)(gb2 + 4096 + 32768);                // 128 KB
  float4* plist    = (float4*)(gb2 + 4096 + 32768 + 131072);    // 128 KB
  int*    tsorted  = (int*)(gb2 + 4096 + 32768 + 2 * 131072);   // 128 KB
  int*    ovfc     = (int*)(gb2 + 4096 + 32768 + 3 * 131072);
  int*    ovf      = (int*)(gb2 + 4096 + 32768 + 3 * 131072 + 1024); // 128 KB

  // ======================= Level 0: 512 -> 2048 ============================
  knn_part<1><<<dim3(8, 16), 256, 0, stream>>>(POS[0], POS[1], 512, 2048, 16, cd, ci);
  merge_gather<512, 0><<<32, 256, 0, stream>>>(cd, ci, 16, X[0], up, 2048, stats, nullptr);
  gemm_k<32, 32, 1, 0><<<dim3(64, 8), 256, 0, stream>>>(
      X[1], up, 256, PRM(0, 0), PRM(0, 1),
      nullptr, nullptr, nullptr, nullptr,
      z1, s1, q1, 2048, 768, 256);
  gemm_k<32, 32, 0, 1><<<dim3(64, 8), 256, 0, stream>>>(
      z1, nullptr, 0, PRM(0, 4), PRM(0, 5),
      s1, q1, PRM(0, 2), PRM(0, 3),
      z2, s2, q2, 2048, 256, 256);
  final_k<<<512, 256, 0, stream>>>(z1, z2, s1, q1, PRM(0, 2), PRM(0, 3),
                                   s2, q2, PRM(0, 6), PRM(0, 7), x1o, 2048, 256);

  // ======================= Level 1: 2048 -> 8192 ===========================
  knn_part<1><<<dim3(32, 32), 256, 0, stream>>>(POS[1], POS[2], 2048, 8192, 32, cd, ci);
  merge_gather<256, 0><<<128, 256, 0, stream>>>(cd, ci, 32, x1o, up, 8192, stats, nullptr);
  gemm_k<32, 32, 1, 0><<<dim3(256, 4), 256, 0, stream>>>(
      X[2], up, 128, PRM(1, 0), PRM(1, 1),
      nullptr, nullptr, nullptr, nullptr,
      z1, s1, q1, 8192, 384, 128);
  gemm_k<32, 32, 0, 1><<<dim3(256, 4), 256, 0, stream>>>(
      z1, nullptr, 0, PRM(1, 4), PRM(1, 5),
      s1, q1, PRM(1, 2), PRM(1, 3),
      z2, s2, q2, 8192, 128, 128);
  final_k<<<1024, 256, 0, stream>>>(z1, z2, s1, q1, PRM(1, 2), PRM(1, 3),
                                    s2, q2, PRM(1, 6), PRM(1, 7), x2o, 8192, 128);

  // ======================= Level 2: 8192 -> 32768 (grid KNN) ===============
  hipMemsetAsync(cnt, 0, 2 * S, stream);                 // cnt + tcnt
  grid_count2<<<dim3(128, 2), 256, 0, stream>>>(POS[2], 8192, cnt, pcell,
                                                POS[3], 32768, tcnt, tpcell);
  grid_scan1<<<dim3(138, 2), 256, 0, stream>>>(cnt, ofsp, aux, tcnt, tofsp, aux2);
  grid_scan2<<<2, 256, 0, stream>>>(aux, auxp, aux2, auxp2, 138);
  grid_fixup2<<<dim3(256, 2), 256, 0, stream>>>(ofsp, auxp, cursor, cellstart, 8192,
                                                tofsp, auxp2, tcursor, ovfc);
  grid_scatter2<<<dim3(128, 2), 256, 0, stream>>>(POS[2], 8192, pcell, cursor, plist,
                                                  32768, tpcell, tcursor, tsorted);
  knn_search_quad<<<512, 256, 0, stream>>>(POS[3], 32768, cellstart, plist,
                                           tsorted, widx, ovfc, ovf);
  knn_brute<<<256, 256, 0, stream>>>(POS[3], plist, 8192, ovfc, ovf, widx);
  merge_gather<128, 1><<<512, 256, 0, stream>>>(nullptr, nullptr, 0, x2o, up,
                                                32768, stats, widx);
  gemm_k<32, 64, 1, 0><<<dim3(1024, 1), 256, 0, stream>>>(
      X[3], up, 64, PRM(2, 0), PRM(2, 1),
      nullptr, nullptr, nullptr, nullptr,
      z1, s1, q1, 32768, 192, 64);
  gemm_k<32, 64, 0, 1><<<dim3(1024, 1), 256, 0, stream>>>(
      z1, nullptr, 0, PRM(2, 4), PRM(2, 5),
      s1, q1, PRM(2, 2), PRM(2, 3),
      z2, s2, q2, 32768, 64, 64);
  final_k<<<1024, 256, 0, stream>>>(z1, z2, s1, q1, PRM(2, 2), PRM(2, 3),
                                    s2, q2, PRM(2, 6), PRM(2, 7),
                                    (float*)d_out, 32768, 64);
}

// Round 10
// 397.277 us; speedup vs baseline: 1.1877x; 1.1877x over previous
//
#include <hip/hip_runtime.h>

// PointNet++-style decoder forward: 3 levels of {knn_interpolate -> concat ->
// Lin+BN+ReLU -> residual Lin+BN+ReLU}. All fp32. Single batch.
// The knn gather is FUSED into gemm1's A-staging (no materialized `up`).

#define EPS_BN 1e-5f
#define EPS_W  1e-16f

// ---- L2 KNN spatial grid parameters (sources = 8192 Gaussian pts) ---------
#define GRD    52
#define GLO   -6.5f
#define GH     0.25f
#define GIH    4.0f
#define NCELLS (GRD * GRD * GRD)   // 140608

typedef unsigned long long u64;

__device__ __forceinline__ void key_insert(u64 nk, u64& k0, u64& k1, u64& k2) {
  bool c = nk < k0; u64 tk = c ? k0 : nk; k0 = c ? nk : k0; nk = tk;
  c = nk < k1; tk = c ? k1 : nk; k1 = c ? nk : k1; nk = tk;
  c = nk < k2; k2 = c ? nk : k2;
}

__device__ __forceinline__ void quad_merge(u64& k0, u64& k1, u64& k2) {
#pragma unroll
  for (int off = 1; off <= 2; off <<= 1) {
    u64 a0 = __shfl_xor(k0, off);
    u64 a1 = __shfl_xor(k1, off);
    u64 a2 = __shfl_xor(k2, off);
    key_insert(a0, k0, k1, k2);
    key_insert(a1, k0, k1, k2);
    key_insert(a2, k0, k1, k2);
  }
}

__device__ __forceinline__ void write_widx(float* widx, int t,
                                           u64 k0, u64 k1, u64 k2) {
  float d0 = __uint_as_float((unsigned)(k0 >> 32));
  float d1 = __uint_as_float((unsigned)(k1 >> 32));
  float d2 = __uint_as_float((unsigned)(k2 >> 32));
  float w0 = 1.f / fmaxf(d0, EPS_W);
  float w1 = 1.f / fmaxf(d1, EPS_W);
  float w2 = 1.f / fmaxf(d2, EPS_W);
  float inv = 1.f / (w0 + w1 + w2);
  *(float4*)&widx[(size_t)t * 8] =
      make_float4(w0 * inv, w1 * inv, w2 * inv, 0.f);
  *(float4*)&widx[(size_t)t * 8 + 4] =
      make_float4(__uint_as_float((unsigned)k0), __uint_as_float((unsigned)k1),
                  __uint_as_float((unsigned)k2), 0.f);
}

// ---------------------------------------------------------------------------
// Fused brute KNN (levels 0,1): block = 64 targets x 4 lanes. Sources staged
// through LDS in 512-point tiles; each quad-lane scans a strided quarter,
// quad butterfly merge, lane 0 writes widx. u64 keys -> exact top_k ties.
// Block 0 zeroes the BN stats accumulators for this level's GEMMs.
// ---------------------------------------------------------------------------
__global__ __launch_bounds__(256)
void knn_fused(const float* __restrict__ pos_s, const float* __restrict__ pos_t,
               int Ns, int Nt, float* __restrict__ widx,
               float* __restrict__ stats0)
{
  __shared__ float4 sp[512];
  if (blockIdx.x == 0) {
    for (int i = threadIdx.x; i < 1024; i += 256) stats0[i] = 0.f;
  }

  int gid = blockIdx.x * 64 + (threadIdx.x >> 2);   // Nt is a multiple of 64
  int sub = threadIdx.x & 3;
  float tx = pos_t[3 * gid], ty = pos_t[3 * gid + 1], tz = pos_t[3 * gid + 2];

  u64 k0 = ~0ULL, k1 = ~0ULL, k2 = ~0ULL;

  for (int base = 0; base < Ns; base += 512) {
    int m = min(512, Ns - base);
    __syncthreads();
    for (int i = threadIdx.x; i < m; i += 256) {
      int p = base + i;
      sp[i] = make_float4(pos_s[3 * p], pos_s[3 * p + 1], pos_s[3 * p + 2], 0.f);
    }
    __syncthreads();
#pragma unroll 4
    for (int j = sub; j < m; j += 4) {
      float4 s = sp[j];
      float dx = tx - s.x, dy = ty - s.y, dz = tz - s.z;
      float d = fmaf(dz, dz, fmaf(dy, dy, dx * dx));
      key_insert(((u64)__float_as_uint(d) << 32) | (u64)(unsigned)(base + j),
                 k0, k1, k2);
    }
  }

  quad_merge(k0, k1, k2);
  if (sub == 0) write_widx(widx, gid, k0, k1, k2);
}

// ---------------------------------------------------------------------------
// Grid build (L2). Fused source/target variants via blockIdx.y.
// ---------------------------------------------------------------------------
__device__ __forceinline__ int cell_coord(float v) {
  return min(max((int)floorf((v - GLO) * GIH), 0), GRD - 1);
}

__global__ __launch_bounds__(256)
void grid_count2(const float* __restrict__ ps, int ns, int* __restrict__ cnt,
                 int* __restrict__ pcell,
                 const float* __restrict__ pt, int nt, int* __restrict__ tcnt,
                 int* __restrict__ tpcell)
{
  int i = blockIdx.x * 256 + threadIdx.x;
  const float* p; int n; int* c; int* pc;
  if (blockIdx.y == 0) { p = ps; n = ns; c = cnt;  pc = pcell; }
  else                 { p = pt; n = nt; c = tcnt; pc = tpcell; }
  if (i >= n) return;
  int cx = cell_coord(p[3 * i + 0]);
  int cy = cell_coord(p[3 * i + 1]);
  int cz = cell_coord(p[3 * i + 2]);
  int cid = (cz * GRD + cy) * GRD + cx;
  pc[i] = cid;
  atomicAdd(&c[cid], 1);
}

__global__ __launch_bounds__(256)
void grid_scan1(const int* __restrict__ cntA, int* __restrict__ ofspA,
                int* __restrict__ auxA,
                const int* __restrict__ cntB, int* __restrict__ ofspB,
                int* __restrict__ auxB)
{
  const int* cnt; int* ofsp; int* aux;
  if (blockIdx.y == 0) { cnt = cntA; ofsp = ofspA; aux = auxA; }
  else                 { cnt = cntB; ofsp = ofspB; aux = auxB; }
  __shared__ int arr[256];
  int tid = threadIdx.x;
  int c0 = blockIdx.x * 1024 + tid * 4;
  int s0 = (c0 + 0 < NCELLS) ? cnt[c0 + 0] : 0;
  int s1 = (c0 + 1 < NCELLS) ? cnt[c0 + 1] : 0;
  int s2 = (c0 + 2 < NCELLS) ? cnt[c0 + 2] : 0;
  int s3 = (c0 + 3 < NCELLS) ? cnt[c0 + 3] : 0;
  int p1 = s0, p2 = s0 + s1, p3 = p2 + s2, tot = p3 + s3;
  arr[tid] = tot; __syncthreads();
  for (int d = 1; d < 256; d <<= 1) {
    int v = (tid >= d) ? arr[tid - d] : 0;
    __syncthreads();
    arr[tid] += v;
    __syncthreads();
  }
  int excl = arr[tid] - tot;
  if (c0 + 0 < NCELLS) ofsp[c0 + 0] = excl;
  if (c0 + 1 < NCELLS) ofsp[c0 + 1] = excl + p1;
  if (c0 + 2 < NCELLS) ofsp[c0 + 2] = excl + p2;
  if (c0 + 3 < NCELLS) ofsp[c0 + 3] = excl + p3;
  if (tid == 255) aux[blockIdx.x] = arr[255];
}

// Fixup with INLINE aux prefix scan (scan2 kernel eliminated): each block
// re-scans the 138-entry aux array in LDS. side 0 also writes cellstart,
// sentinel, ovfc=0 and zeroes the BN stats for this level.
__global__ __launch_bounds__(256)
void grid_fixup2(const int* __restrict__ ofsp, const int* __restrict__ aux,
                 int* __restrict__ cursor, int* __restrict__ cellstart,
                 int ns_total,
                 const int* __restrict__ tofsp, const int* __restrict__ taux,
                 int* __restrict__ tcursor, int* __restrict__ ovf_cnt,
                 float* __restrict__ stats0)
{
  __shared__ int arr[256];
  __shared__ int auxp_l[140];
  const int* ax = (blockIdx.y == 0) ? aux : taux;
  int tid = threadIdx.x;
  int v = (tid < 138) ? ax[tid] : 0;
  arr[tid] = v; __syncthreads();
  for (int d = 1; d < 256; d <<= 1) {
    int w = (tid >= d) ? arr[tid - d] : 0;
    __syncthreads();
    arr[tid] += w;
    __syncthreads();
  }
  if (tid < 138) auxp_l[tid] = arr[tid] - v;   // exclusive
  __syncthreads();

  int i = blockIdx.x * 256 + tid;
  if (blockIdx.y == 0) {
    if (blockIdx.x == 0) {
      if (tid == 0) { *ovf_cnt = 0; cellstart[NCELLS] = ns_total; }
      for (int s = tid; s < 1024; s += 256) stats0[s] = 0.f;
    }
    for (int c = i; c < NCELLS; c += gridDim.x * 256) {
      int vv = ofsp[c] + auxp_l[c >> 10];
      cursor[c] = vv;
      cellstart[c] = vv;
    }
  } else {
    for (int c = i; c < NCELLS; c += gridDim.x * 256)
      tcursor[c] = tofsp[c] + auxp_l[c >> 10];
  }
}

// side 0: scatter source points as float4(pos,idx); side 1: target index sort.
__global__ __launch_bounds__(256)
void grid_scatter2(const float* __restrict__ ps, int ns,
                   const int* __restrict__ pcell, int* __restrict__ cursor,
                   float4* __restrict__ plist,
                   int nt, const int* __restrict__ tpcell,
                   int* __restrict__ tcursor, int* __restrict__ tsorted)
{
  int i = blockIdx.x * 256 + threadIdx.x;
  if (blockIdx.y == 0) {
    if (i >= ns) return;
    int slot = atomicAdd(&cursor[pcell[i]], 1);
    plist[slot] = make_float4(ps[3 * i], ps[3 * i + 1], ps[3 * i + 2],
                              __uint_as_float((unsigned)i));
  } else {
    if (i >= nt) return;
    int slot = atomicAdd(&tcursor[tpcell[i]], 1);
    tsorted[slot] = i;
  }
}

// ---------------------------------------------------------------------------
// L2 KNN search, quad-per-target (see R7 notes). Exact u64 keys; certify at
// r=1,2 via cube-face lower bound; unresolved -> overflow (exact brute).
// ---------------------------------------------------------------------------
__global__ __launch_bounds__(256)
void knn_search_quad(const float* __restrict__ pos_t, int Nt,
                     const int* __restrict__ cellstart,
                     const float4* __restrict__ plist,
                     const int* __restrict__ tsorted,
                     float* __restrict__ widx,
                     int* __restrict__ ovf_cnt, int* __restrict__ ovf)
{
  int gid = blockIdx.x * 64 + (threadIdx.x >> 2);   // 64 targets per block
  int sub = threadIdx.x & 3;
  if (gid >= Nt) return;
  int t = tsorted[gid];
  float tx = pos_t[3 * t], ty = pos_t[3 * t + 1], tz = pos_t[3 * t + 2];
  int cx = cell_coord(tx), cy = cell_coord(ty), cz = cell_coord(tz);

  u64 k0 = ~0ULL, k1 = ~0ULL, k2 = ~0ULL;

  auto scan_range = [&](int p0, int p1, u64& a0, u64& a1, u64& a2) {
    for (int p = p0; p < p1; ++p) {
      float4 s = plist[p];
      float dx = tx - s.x, dy = ty - s.y, dz = tz - s.z;
      float d = fmaf(dz, dz, fmaf(dy, dy, dx * dx));
      key_insert(((u64)__float_as_uint(d) << 32) | (u64)__float_as_uint(s.w),
                 a0, a1, a2);
    }
  };

  auto certify = [&](int R) -> bool {
    int xl = max(cx - R, 0), xh = min(cx + R, GRD - 1);
    int yl = max(cy - R, 0), yh = min(cy + R, GRD - 1);
    int zl = max(cz - R, 0), zh = min(cz + R, GRD - 1);
    float m = 1e30f;
    if (xl > 0)       m = fminf(m, tx - (GLO + xl * GH));
    if (xh < GRD - 1) m = fminf(m, (GLO + (xh + 1) * GH) - tx);
    if (yl > 0)       m = fminf(m, ty - (GLO + yl * GH));
    if (yh < GRD - 1) m = fminf(m, (GLO + (yh + 1) * GH) - ty);
    if (zl > 0)       m = fminf(m, tz - (GLO + zl * GH));
    if (zh < GRD - 1) m = fminf(m, (GLO + (zh + 1) * GH) - tz);
    float d2b = __uint_as_float((unsigned)(k2 >> 32));   // NaN if <3 found
    return (m * m * 0.9999f > d2b);                      // NaN -> false
  };

  // Phase 1: 9 rows split across the quad
  int xlo = max(cx - 1, 0), xhi = min(cx + 1, GRD - 1);
  for (int id = sub; id < 9; id += 4) {
    int y = cy + (id % 3) - 1, z = cz + (id / 3) - 1;
    if (((unsigned)y < GRD) && ((unsigned)z < GRD)) {
      int base = (z * GRD + y) * GRD;
      scan_range(cellstart[base + xlo], cellstart[base + xhi + 1], k0, k1, k2);
    }
  }
  quad_merge(k0, k1, k2);
  bool done = certify(1);

  if (!done) {
    // Phase 2: r=2 shell (fresh disjoint keys -> butterfly -> cross merge)
    static const signed char o_dy[16] = {-2,-1,0,1,2, -2,-1,0,1,2, -2,-2,-2, 2,2,2};
    static const signed char o_dz[16] = {-2,-2,-2,-2,-2, 2,2,2,2,2, -1,0,1, -1,0,1};
    int xl2 = max(cx - 2, 0), xh2 = min(cx + 2, GRD - 1);
    u64 p0 = ~0ULL, p1 = ~0ULL, p2 = ~0ULL;
    for (int id = sub; id < 34; id += 4) {
      if (id < 16) {
        int y = cy + o_dy[id], z = cz + o_dz[id];
        if (((unsigned)y < GRD) && ((unsigned)z < GRD)) {
          int base = (z * GRD + y) * GRD;
          scan_range(cellstart[base + xl2], cellstart[base + xh2 + 1], p0, p1, p2);
        }
      } else {
        int row = (id - 16) >> 1, side = (id - 16) & 1;
        int y = cy + (row % 3) - 1, z = cz + (row / 3) - 1;
        int x = side ? (cx + 2) : (cx - 2);
        if (((unsigned)y < GRD) && ((unsigned)z < GRD) && ((unsigned)x < GRD)) {
          int base = (z * GRD + y) * GRD;
          scan_range(cellstart[base + x], cellstart[base + x + 1], p0, p1, p2);
        }
      }
    }
    quad_merge(p0, p1, p2);
    key_insert(p0, k0, k1, k2);
    key_insert(p1, k0, k1, k2);
    key_insert(p2, k0, k1, k2);
    done = certify(2);
  }

  if (!done) {
    if (sub == 0) ovf[atomicAdd(ovf_cnt, 1)] = t;
    return;
  }
  if (sub == 0) write_widx(widx, t, k0, k1, k2);
}

// ---------------------------------------------------------------------------
// Brute fallback: 4 targets/block, LDS-tiled sources, wave-tree shfl merge.
// ---------------------------------------------------------------------------
__global__ __launch_bounds__(256)
void knn_brute(const float* __restrict__ pos_t, const float4* __restrict__ plist,
               int Ns, const int* __restrict__ ovf_cnt,
               const int* __restrict__ ovf, float* __restrict__ widx)
{
  __shared__ float4 tile[1024];
  int n = *ovf_cnt;
  int ngrp = (n + 3) >> 2;
  int wv = threadIdx.x >> 6, ln = threadIdx.x & 63;

  for (int g = blockIdx.x; g < ngrp; g += gridDim.x) {
    int o = g * 4 + wv;
    bool active = (o < n);
    int t = active ? ovf[o] : 0;
    float tx = pos_t[3 * t], ty = pos_t[3 * t + 1], tz = pos_t[3 * t + 2];
    u64 k0 = ~0ULL, k1 = ~0ULL, k2 = ~0ULL;

    for (int base = 0; base < Ns; base += 1024) {
      int m = min(1024, Ns - base);
      __syncthreads();
      for (int i = threadIdx.x; i < m; i += 256) tile[i] = plist[base + i];
      __syncthreads();
#pragma unroll 4
      for (int p = ln; p < m; p += 64) {
        float4 s = tile[p];
        float dx = tx - s.x, dy = ty - s.y, dz = tz - s.z;
        float d = fmaf(dz, dz, fmaf(dy, dy, dx * dx));
        key_insert(((u64)__float_as_uint(d) << 32) | (u64)__float_as_uint(s.w),
                   k0, k1, k2);
      }
    }

#pragma unroll
    for (int off = 32; off >= 1; off >>= 1) {
      u64 a0 = __shfl_down(k0, off);
      u64 a1 = __shfl_down(k1, off);
      u64 a2 = __shfl_down(k2, off);
      key_insert(a0, k0, k1, k2);
      key_insert(a1, k0, k1, k2);
      key_insert(a2, k0, k1, k2);
    }
    if (active && ln == 0) write_widx(widx, t, k0, k1, k2);
  }
}

// ---------------------------------------------------------------------------
// fp32 tiled GEMM v3: Z[m][n] = sum_k A[m][k]*B[n][k] + bias[n].
// CONCAT: A = [A0 (C0 cols) | interp(xs, widx)] — the knn-interpolated half
// is GATHERED ON THE FLY during A-staging (3 weighted xs rows per A-row),
// hidden under the FMA loop by the register prefetch.
// BNIN: A = relu(bn(A0)). Conflict-free LDS; fused BN-stats epilogue.
// ---------------------------------------------------------------------------
template<int BM, int BN, int CONCAT, int BNIN>
__global__ __launch_bounds__(256, 4)
void gemm_k(const float* __restrict__ A0, const float* __restrict__ xs,
            const float* __restrict__ wvec, int C0, int ldx,
            const float* __restrict__ B, const float* __restrict__ bias,
            const float* __restrict__ s_in, const float* __restrict__ q_in,
            const float* __restrict__ g_in, const float* __restrict__ be_in,
            float* __restrict__ Z, float* __restrict__ s_out, float* __restrict__ q_out,
            int M, int K, int N)
{
  const int BK = 32;
  const int TN = BN / 4;          // column-group threads
  const int TM = 256 / TN;        // row threads
  const int AR = BM / TM;         // rows per thread
  const int NA = BM / 32;         // A float4 loads per thread
  const int NB = BN / 32;         // B float4 loads per thread

  __shared__ alignas(16) float a_lds[BM][BK + 4];
  __shared__ float b_lds[BK][BN + 1];
  __shared__ float bn_sc[256], bn_sh[256];

  const int tid = threadIdx.x;
  const int tn = tid % TN, tm = tid / TN;
  const int mb = blockIdx.x * BM;
  const int nb = blockIdx.y * BN;

  if (BNIN) {
    for (int c = tid; c < K; c += 256) {
      float mean = s_in[c] / (float)M;
      float var  = q_in[c] / (float)M - mean * mean;
      float rstd = rsqrtf(var + EPS_BN);
      float sc = g_in[c] * rstd;
      bn_sc[c] = sc;
      bn_sh[c] = be_in[c] - mean * sc;
    }
    __syncthreads();
  }

  float acc[AR][4];
#pragma unroll
  for (int i = 0; i < AR; ++i)
#pragma unroll
    for (int j = 0; j < 4; ++j) acc[i][j] = 0.f;

  float4 pa[NA], pb[NB];

  auto prefetch = [&](int kb) {
    if (CONCAT && kb >= C0) {
      int ko = kb - C0;
#pragma unroll
      for (int i = 0; i < NA; ++i) {
        int sl = tid + 256 * i;
        int m = sl >> 3, k4 = (sl & 7) * 4;
        int t = mb + m;
        float4 wvv = *(const float4*)&wvec[(size_t)t * 8];
        float4 ivv = *(const float4*)&wvec[(size_t)t * 8 + 4];
        const float4 r0 = *(const float4*)(xs + (size_t)__float_as_uint(ivv.x) * ldx + ko + k4);
        const float4 r1 = *(const float4*)(xs + (size_t)__float_as_uint(ivv.y) * ldx + ko + k4);
        const float4 r2 = *(const float4*)(xs + (size_t)__float_as_uint(ivv.z) * ldx + ko + k4);
        pa[i].x = wvv.x * r0.x + wvv.y * r1.x + wvv.z * r2.x;
        pa[i].y = wvv.x * r0.y + wvv.y * r1.y + wvv.z * r2.y;
        pa[i].z = wvv.x * r0.z + wvv.y * r1.z + wvv.z * r2.z;
        pa[i].w = wvv.x * r0.w + wvv.y * r1.w + wvv.z * r2.w;
      }
    } else {
      int ldA = CONCAT ? C0 : K;
#pragma unroll
      for (int i = 0; i < NA; ++i) {
        int sl = tid + 256 * i;
        int m = sl >> 3, k4 = (sl & 7) * 4;
        pa[i] = *(const float4*)(A0 + (size_t)(mb + m) * ldA + kb + k4);
      }
    }
#pragma unroll
    for (int i = 0; i < NB; ++i) {
      int sl = tid + 256 * i;
      int nn = sl >> 3, k4 = (sl & 7) * 4;
      pb[i] = *(const float4*)(B + (size_t)(nb + nn) * K + kb + k4);
    }
  };

  prefetch(0);

  for (int kb = 0; kb < K; kb += BK) {
#pragma unroll
    for (int i = 0; i < NA; ++i) {
      int sl = tid + 256 * i;
      int m = sl >> 3, k4 = (sl & 7) * 4;
      float4 v = pa[i];
      if (BNIN) {
        v.x = fmaxf(v.x * bn_sc[kb + k4 + 0] + bn_sh[kb + k4 + 0], 0.f);
        v.y = fmaxf(v.y * bn_sc[kb + k4 + 1] + bn_sh[kb + k4 + 1], 0.f);
        v.z = fmaxf(v.z * bn_sc[kb + k4 + 2] + bn_sh[kb + k4 + 2], 0.f);
        v.w = fmaxf(v.w * bn_sc[kb + k4 + 3] + bn_sh[kb + k4 + 3], 0.f);
      }
      *(float4*)&a_lds[m][k4] = v;
    }
#pragma unroll
    for (int i = 0; i < NB; ++i) {
      int sl = tid + 256 * i;
      int nn = sl >> 3, k4 = (sl & 7) * 4;
      float4 v = pb[i];
      b_lds[k4 + 0][nn] = v.x; b_lds[k4 + 1][nn] = v.y;
      b_lds[k4 + 2][nn] = v.z; b_lds[k4 + 3][nn] = v.w;
    }
    __syncthreads();
    if (kb + BK < K) prefetch(kb + BK);   // overlaps with FMA loop

#pragma unroll
    for (int k = 0; k < BK; ++k) {
      float bv0 = b_lds[k][tn * 4 + 0];
      float bv1 = b_lds[k][tn * 4 + 1];
      float bv2 = b_lds[k][tn * 4 + 2];
      float bv3 = b_lds[k][tn * 4 + 3];
#pragma unroll
      for (int i = 0; i < AR; ++i) {
        float a = a_lds[tm * AR + i][k];
        acc[i][0] = fmaf(a, bv0, acc[i][0]);
        acc[i][1] = fmaf(a, bv1, acc[i][1]);
        acc[i][2] = fmaf(a, bv2, acc[i][2]);
        acc[i][3] = fmaf(a, bv3, acc[i][3]);
      }
    }
    __syncthreads();
  }

  // epilogue: bias add, store, per-column partial stats
  float4 bb = *(const float4*)&bias[nb + tn * 4];
  float psum[4] = {0, 0, 0, 0}, psq[4] = {0, 0, 0, 0};
#pragma unroll
  for (int i = 0; i < AR; ++i) {
    int m = tm * AR + i;
    float4 v;
    v.x = acc[i][0] + bb.x; v.y = acc[i][1] + bb.y;
    v.z = acc[i][2] + bb.z; v.w = acc[i][3] + bb.w;
    *(float4*)(Z + (size_t)(mb + m) * N + nb + tn * 4) = v;
    psum[0] += v.x; psum[1] += v.y; psum[2] += v.z; psum[3] += v.w;
    psq[0] += v.x * v.x; psq[1] += v.y * v.y;
    psq[2] += v.z * v.z; psq[3] += v.w * v.w;
  }
  __syncthreads();
  float* red_s = &b_lds[0][0];   // BK*(BN+1) >= BN*TM
  float* red_q = &a_lds[0][0];   // BM*(BK+4) >= BN*TM
#pragma unroll
  for (int j = 0; j < 4; ++j) {
    int c = tn * 4 + j;
    red_s[c * TM + tm] = psum[j];
    red_q[c * TM + tm] = psq[j];
  }
  __syncthreads();
  if (tid < BN) {
    float s = 0.f, q = 0.f;
#pragma unroll
    for (int it = 0; it < TM; ++it) {
      s += red_s[tid * TM + it];
      q += red_q[tid * TM + it];
    }
    atomicAdd(&s_out[nb + tid], s);
    atomicAdd(&q_out[nb + tid], q);
  }
}

// ---------------------------------------------------------------------------
// Final elementwise per level: out = relu(bn1(z1)) + relu(bn2(z2)).
// Optional tail: zero `zbuf[0..zn)` (used by L1 to clear L2's grid counters).
// ---------------------------------------------------------------------------
__global__ __launch_bounds__(256)
void final_k(const float* __restrict__ z1, const float* __restrict__ z2,
             const float* __restrict__ s1, const float* __restrict__ q1,
             const float* __restrict__ g1, const float* __restrict__ be1,
             const float* __restrict__ s2, const float* __restrict__ q2,
             const float* __restrict__ g2, const float* __restrict__ be2,
             float* __restrict__ outp, int M, int C,
             int* __restrict__ zbuf, int zn)
{
  __shared__ float sc1[256], sh1[256], sc2[256], sh2[256];
  for (int c = threadIdx.x; c < C; c += 256) {
    float mean = s1[c] / (float)M;
    float var  = q1[c] / (float)M - mean * mean;
    float r = rsqrtf(var + EPS_BN);
    sc1[c] = g1[c] * r; sh1[c] = be1[c] - mean * sc1[c];
    mean = s2[c] / (float)M;
    var  = q2[c] / (float)M - mean * mean;
    r = rsqrtf(var + EPS_BN);
    sc2[c] = g2[c] * r; sh2[c] = be2[c] - mean * sc2[c];
  }
  __syncthreads();

  if (zbuf) {
    int gtid = blockIdx.x * 256 + threadIdx.x;
    for (int i = gtid; i < zn; i += gridDim.x * 256) zbuf[i] = 0;
  }

  int total4 = M * C / 4;
  int cmask = (C / 4) - 1;                   // C/4 is a power of two
  for (int i = blockIdx.x * 256 + threadIdx.x; i < total4; i += gridDim.x * 256) {
    int c = (i & cmask) * 4;
    float4 a = ((const float4*)z1)[i];
    float4 b = ((const float4*)z2)[i];
    float4 r;
    r.x = fmaxf(a.x * sc1[c + 0] + sh1[c + 0], 0.f) + fmaxf(b.x * sc2[c + 0] + sh2[c + 0], 0.f);
    r.y = fmaxf(a.y * sc1[c + 1] + sh1[c + 1], 0.f) + fmaxf(b.y * sc2[c + 1] + sh2[c + 1], 0.f);
    r.z = fmaxf(a.z * sc1[c + 2] + sh1[c + 2], 0.f) + fmaxf(b.z * sc2[c + 2] + sh2[c + 2], 0.f);
    r.w = fmaxf(a.w * sc1[c + 3] + sh1[c + 3], 0.f) + fmaxf(b.w * sc2[c + 3] + sh2[c + 3], 0.f);
    ((float4*)outp)[i] = r;
  }
}

// ---------------------------------------------------------------------------
extern "C" void kernel_launch(void* const* d_in, const int* in_sizes, int n_in,
                              void* d_out, int out_size, void* d_ws, size_t ws_size,
                              hipStream_t stream)
{
  const bool dict_order = (in_sizes[1] == 512 * 512);

  const float* POS[4];
  const float* X[4];
  for (int i = 0; i < 4; ++i) {
    POS[i] = (const float*)d_in[dict_order ? 3 * i : i];
    X[i]   = (const float*)d_in[dict_order ? 3 * i + 1 : 4 + i];
  }
  static const int dict_map[8] = {0, 2, 6, 3, 1, 4, 7, 5};
  auto PRM = [&](int lvl, int which) -> const float* {
    int idx = dict_order ? (12 + 8 * lvl + dict_map[which]) : (8 + 8 * lvl + which);
    return (const float*)d_in[idx];
  };

  // Workspace layout (~31.2 MB, all regions disjoint; no `up` buffer):
  char* ws = (char*)d_ws;
  float* z1    = (float*)(ws);                          // 8 MB max
  float* z2    = (float*)(ws + (8u << 20));             // 8 MB max
  float* x1o   = (float*)(ws + (16u << 20));            // 2 MB
  float* x2o   = (float*)(ws + (18u << 20));            // 4 MB
  float* stats = (float*)(ws + (22u << 20));            // 4 KB (pad 8 KB)
  float* s1 = stats, *q1 = stats + 256, *s2 = stats + 512, *q2 = stats + 768;
  char*  wb   = ws + (22u << 20) + 8192;
  float* widx0 = (float*)(wb);                          // 64 KB
  float* widx1 = (float*)(wb + 65536);                  // 256 KB
  float* widx2 = (float*)(wb + 65536 + 262144);         // 1 MB

  char* gb = ws + (24u << 20);
  const size_t S = 600 * 1024;
  int*    ofsp     = (int*)(gb + 0 * S);
  int*    tofsp    = (int*)(gb + 1 * S);
  int*    cursor   = (int*)(gb + 2 * S);
  int*    tcursor  = (int*)(gb + 3 * S);
  int*    cellstart= (int*)(gb + 4 * S);                // NCELLS+1 ints
  char*   gb2      = gb + 5 * S;
  int*    aux      = (int*)(gb2);
  int*    aux2     = (int*)(gb2 + 1024);
  int*    pcell    = (int*)(gb2 + 4096);                        // 32 KB
  int*    tpcell   = (int*)(gb2 + 4096 + 32768);                // 128 KB
  float4* plist    = (float4*)(gb2 + 4096 + 32768 + 131072);    // 128 KB
  int*    tsorted  = (int*)(gb2 + 4096 + 32768 + 2 * 131072);   // 128 KB
  int*    ovfc     = (int*)(gb2 + 4096 + 32768 + 3 * 131072);
  int*    ovf      = (int*)(gb2 + 4096 + 32768 + 3 * 131072 + 1024); // 128 KB
  int*    cnt      = (int*)(ws + (30u << 20));          // S (zeroed by L1 final)
  int*    tcnt     = (int*)(ws + (30u << 20) + S);      // S

  // ======================= Level 0: 512 -> 2048 ============================
  knn_fused<<<32, 256, 0, stream>>>(POS[0], POS[1], 512, 2048, widx0, stats);
  gemm_k<32, 64, 1, 0><<<dim3(64, 4), 256, 0, stream>>>(
      X[1], X[0], widx0, 256, 512, PRM(0, 0), PRM(0, 1),
      nullptr, nullptr, nullptr, nullptr,
      z1, s1, q1, 2048, 768, 256);
  gemm_k<32, 64, 0, 1><<<dim3(64, 4), 256, 0, stream>>>(
      z1, nullptr, nullptr, 0, 0, PRM(0, 4), PRM(0, 5),
      s1, q1, PRM(0, 2), PRM(0, 3),
      z2, s2, q2, 2048, 256, 256);
  final_k<<<512, 256, 0, stream>>>(z1, z2, s1, q1, PRM(0, 2), PRM(0, 3),
                                   s2, q2, PRM(0, 6), PRM(0, 7), x1o, 2048, 256,
                                   nullptr, 0);

  // ======================= Level 1: 2048 -> 8192 ===========================
  knn_fused<<<128, 256, 0, stream>>>(POS[1], POS[2], 2048, 8192, widx1, stats);
  gemm_k<32, 64, 1, 0><<<dim3(256, 2), 256, 0, stream>>>(
      X[2], x1o, widx1, 128, 256, PRM(1, 0), PRM(1, 1),
      nullptr, nullptr, nullptr, nullptr,
      z1, s1, q1, 8192, 384, 128);
  gemm_k<32, 64, 0, 1><<<dim3(256, 2), 256, 0, stream>>>(
      z1, nullptr, nullptr, 0, 0, PRM(1, 4), PRM(1, 5),
      s1, q1, PRM(1, 2), PRM(1, 3),
      z2, s2, q2, 8192, 128, 128);
  final_k<<<1024, 256, 0, stream>>>(z1, z2, s1, q1, PRM(1, 2), PRM(1, 3),
                                    s2, q2, PRM(1, 6), PRM(1, 7), x2o, 8192, 128,
                                    cnt, (int)(2 * S / 4));   // zero cnt+tcnt

  // ======================= Level 2: 8192 -> 32768 (grid KNN) ===============
  grid_count2<<<dim3(128, 2), 256, 0, stream>>>(POS[2], 8192, cnt, pcell,
                                                POS[3], 32768, tcnt, tpcell);
  grid_scan1<<<dim3(138, 2), 256, 0, stream>>>(cnt, ofsp, aux, tcnt, tofsp, aux2);
  grid_fixup2<<<dim3(256, 2), 256, 0, stream>>>(ofsp, aux, cursor, cellstart, 8192,
                                                tofsp, aux2, tcursor, ovfc, stats);
  grid_scatter2<<<dim3(128, 2), 256, 0, stream>>>(POS[2], 8192, pcell, cursor, plist,
                                                  32768, tpcell, tcursor, tsorted);
  knn_search_quad<<<512, 256, 0, stream>>>(POS[3], 32768, cellstart, plist,
                                           tsorted, widx2, ovfc, ovf);
  knn_brute<<<256, 256, 0, stream>>>(POS[3], plist, 8192, ovfc, ovf, widx2);
  gemm_k<64, 64, 1, 0><<<dim3(512, 1), 256, 0, stream>>>(
      X[3], x2o, widx2, 64, 128, PRM(2, 0), PRM(2, 1),
      nullptr, nullptr, nullptr, nullptr,
      z1, s1, q1, 32768, 192, 64);
  gemm_k<64, 64, 0, 1><<<dim3(512, 1), 256, 0, stream>>>(
      z1, nullptr, nullptr, 0, 0, PRM(2, 4), PRM(2, 5),
      s1, q1, PRM(2, 2), PRM(2, 3),
      z2, s2, q2, 32768, 64, 64);
  final_k<<<1024, 256, 0, stream>>>(z1, z2, s1, q1, PRM(2, 2), PRM(2, 3),
                                    s2, q2, PRM(2, 6), PRM(2, 7),
                                    (float*)d_out, 32768, 64, nullptr, 0);
}

// Round 12
// 375.597 us; speedup vs baseline: 1.2562x; 1.0577x over previous
//
#include <hip/hip_runtime.h>

// PointNet++-style decoder forward: 3 levels of {knn_interpolate -> concat ->
// Lin+BN+ReLU -> residual Lin+BN+ReLU}. All fp32. Single batch.
// The knn gather is FUSED into gemm1's A-staging (no materialized `up`).

#define EPS_BN 1e-5f
#define EPS_W  1e-16f

// ---- L2 KNN spatial grid parameters (sources = 8192 Gaussian pts) ---------
#define GRD    52
#define GLO   -6.5f
#define GH     0.25f
#define GIH    4.0f
#define NCELLS (GRD * GRD * GRD)   // 140608

typedef unsigned long long u64;

__device__ __forceinline__ void key_insert(u64 nk, u64& k0, u64& k1, u64& k2) {
  bool c = nk < k0; u64 tk = c ? k0 : nk; k0 = c ? nk : k0; nk = tk;
  c = nk < k1; tk = c ? k1 : nk; k1 = c ? nk : k1; nk = tk;
  c = nk < k2; k2 = c ? nk : k2;
}

__device__ __forceinline__ void write_widx(float* widx, int t,
                                           u64 k0, u64 k1, u64 k2) {
  float d0 = __uint_as_float((unsigned)(k0 >> 32));
  float d1 = __uint_as_float((unsigned)(k1 >> 32));
  float d2 = __uint_as_float((unsigned)(k2 >> 32));
  float w0 = 1.f / fmaxf(d0, EPS_W);
  float w1 = 1.f / fmaxf(d1, EPS_W);
  float w2 = 1.f / fmaxf(d2, EPS_W);
  float inv = 1.f / (w0 + w1 + w2);
  *(float4*)&widx[(size_t)t * 8] =
      make_float4(w0 * inv, w1 * inv, w2 * inv, 0.f);
  *(float4*)&widx[(size_t)t * 8 + 4] =
      make_float4(__uint_as_float((unsigned)k0), __uint_as_float((unsigned)k1),
                  __uint_as_float((unsigned)k2), 0.f);
}

// ---------------------------------------------------------------------------
// Fused brute KNN (levels 0,1): block = (256>>LG) targets x (1<<LG) lanes.
// Sources staged through LDS in 512-point tiles; each lane scans a strided
// 1/L share, butterfly merge over L lanes, lane 0 writes widx. u64 keys ->
// exact top_k tie handling (disjoint lane sets -> no duplicate keys).
// Block 0 zeroes the BN stats accumulators for this level's GEMMs.
// ---------------------------------------------------------------------------
template<int LG>
__global__ __launch_bounds__(256)
void knn_fused(const float* __restrict__ pos_s, const float* __restrict__ pos_t,
               int Ns, int Nt, float* __restrict__ widx,
               float* __restrict__ stats0)
{
  const int L = 1 << LG;
  __shared__ float4 sp[512];
  if (blockIdx.x == 0) {
    for (int i = threadIdx.x; i < 1024; i += 256) stats0[i] = 0.f;
  }

  int gid = blockIdx.x * (256 >> LG) + (threadIdx.x >> LG);
  int sub = threadIdx.x & (L - 1);
  float tx = pos_t[3 * gid], ty = pos_t[3 * gid + 1], tz = pos_t[3 * gid + 2];

  u64 k0 = ~0ULL, k1 = ~0ULL, k2 = ~0ULL;

  for (int base = 0; base < Ns; base += 512) {
    int m = min(512, Ns - base);
    __syncthreads();
    for (int i = threadIdx.x; i < m; i += 256) {
      int p = base + i;
      sp[i] = make_float4(pos_s[3 * p], pos_s[3 * p + 1], pos_s[3 * p + 2], 0.f);
    }
    __syncthreads();
#pragma unroll 4
    for (int j = sub; j < m; j += L) {
      float4 s = sp[j];
      float dx = tx - s.x, dy = ty - s.y, dz = tz - s.z;
      float d = fmaf(dz, dz, fmaf(dy, dy, dx * dx));
      key_insert(((u64)__float_as_uint(d) << 32) | (u64)(unsigned)(base + j),
                 k0, k1, k2);
    }
  }

#pragma unroll
  for (int off = 1; off < L; off <<= 1) {
    u64 a0 = __shfl_xor(k0, off);
    u64 a1 = __shfl_xor(k1, off);
    u64 a2 = __shfl_xor(k2, off);
    key_insert(a0, k0, k1, k2);
    key_insert(a1, k0, k1, k2);
    key_insert(a2, k0, k1, k2);
  }
  if (sub == 0) write_widx(widx, gid, k0, k1, k2);
}

__device__ __forceinline__ void quad_merge(u64& k0, u64& k1, u64& k2) {
#pragma unroll
  for (int off = 1; off <= 2; off <<= 1) {
    u64 a0 = __shfl_xor(k0, off);
    u64 a1 = __shfl_xor(k1, off);
    u64 a2 = __shfl_xor(k2, off);
    key_insert(a0, k0, k1, k2);
    key_insert(a1, k0, k1, k2);
    key_insert(a2, k0, k1, k2);
  }
}

// ---------------------------------------------------------------------------
// Grid build (L2). Fused source/target variants via blockIdx.y.
// ---------------------------------------------------------------------------
__device__ __forceinline__ int cell_coord(float v) {
  return min(max((int)floorf((v - GLO) * GIH), 0), GRD - 1);
}

__global__ __launch_bounds__(256)
void grid_count2(const float* __restrict__ ps, int ns, int* __restrict__ cnt,
                 int* __restrict__ pcell,
                 const float* __restrict__ pt, int nt, int* __restrict__ tcnt,
                 int* __restrict__ tpcell)
{
  int i = blockIdx.x * 256 + threadIdx.x;
  const float* p; int n; int* c; int* pc;
  if (blockIdx.y == 0) { p = ps; n = ns; c = cnt;  pc = pcell; }
  else                 { p = pt; n = nt; c = tcnt; pc = tpcell; }
  if (i >= n) return;
  int cx = cell_coord(p[3 * i + 0]);
  int cy = cell_coord(p[3 * i + 1]);
  int cz = cell_coord(p[3 * i + 2]);
  int cid = (cz * GRD + cy) * GRD + cx;
  pc[i] = cid;
  atomicAdd(&c[cid], 1);
}

__global__ __launch_bounds__(256)
void grid_scan1(const int* __restrict__ cntA, int* __restrict__ ofspA,
                int* __restrict__ auxA,
                const int* __restrict__ cntB, int* __restrict__ ofspB,
                int* __restrict__ auxB)
{
  const int* cnt; int* ofsp; int* aux;
  if (blockIdx.y == 0) { cnt = cntA; ofsp = ofspA; aux = auxA; }
  else                 { cnt = cntB; ofsp = ofspB; aux = auxB; }
  __shared__ int arr[256];
  int tid = threadIdx.x;
  int c0 = blockIdx.x * 1024 + tid * 4;
  int s0 = (c0 + 0 < NCELLS) ? cnt[c0 + 0] : 0;
  int s1 = (c0 + 1 < NCELLS) ? cnt[c0 + 1] : 0;
  int s2 = (c0 + 2 < NCELLS) ? cnt[c0 + 2] : 0;
  int s3 = (c0 + 3 < NCELLS) ? cnt[c0 + 3] : 0;
  int p1 = s0, p2 = s0 + s1, p3 = p2 + s2, tot = p3 + s3;
  arr[tid] = tot; __syncthreads();
  for (int d = 1; d < 256; d <<= 1) {
    int v = (tid >= d) ? arr[tid - d] : 0;
    __syncthreads();
    arr[tid] += v;
    __syncthreads();
  }
  int excl = arr[tid] - tot;
  if (c0 + 0 < NCELLS) ofsp[c0 + 0] = excl;
  if (c0 + 1 < NCELLS) ofsp[c0 + 1] = excl + p1;
  if (c0 + 2 < NCELLS) ofsp[c0 + 2] = excl + p2;
  if (c0 + 3 < NCELLS) ofsp[c0 + 3] = excl + p3;
  if (tid == 255) aux[blockIdx.x] = arr[255];
}

// Fixup with INLINE aux prefix scan: each block re-scans the 138-entry aux
// array in LDS. side 0 also writes cellstart, sentinel, ovfc=0, BN stats.
__global__ __launch_bounds__(256)
void grid_fixup2(const int* __restrict__ ofsp, const int* __restrict__ aux,
                 int* __restrict__ cursor, int* __restrict__ cellstart,
                 int ns_total,
                 const int* __restrict__ tofsp, const int* __restrict__ taux,
                 int* __restrict__ tcursor, int* __restrict__ ovf_cnt,
                 float* __restrict__ stats0)
{
  __shared__ int arr[256];
  __shared__ int auxp_l[140];
  const int* ax = (blockIdx.y == 0) ? aux : taux;
  int tid = threadIdx.x;
  int v = (tid < 138) ? ax[tid] : 0;
  arr[tid] = v; __syncthreads();
  for (int d = 1; d < 256; d <<= 1) {
    int w = (tid >= d) ? arr[tid - d] : 0;
    __syncthreads();
    arr[tid] += w;
    __syncthreads();
  }
  if (tid < 138) auxp_l[tid] = arr[tid] - v;   // exclusive
  __syncthreads();

  int i = blockIdx.x * 256 + tid;
  if (blockIdx.y == 0) {
    if (blockIdx.x == 0) {
      if (tid == 0) { *ovf_cnt = 0; cellstart[NCELLS] = ns_total; }
      for (int s = tid; s < 1024; s += 256) stats0[s] = 0.f;
    }
    for (int c = i; c < NCELLS; c += gridDim.x * 256) {
      int vv = ofsp[c] + auxp_l[c >> 10];
      cursor[c] = vv;
      cellstart[c] = vv;
    }
  } else {
    for (int c = i; c < NCELLS; c += gridDim.x * 256)
      tcursor[c] = tofsp[c] + auxp_l[c >> 10];
  }
}

// side 0: scatter source points as float4(pos,idx); side 1: target index sort.
__global__ __launch_bounds__(256)
void grid_scatter2(const float* __restrict__ ps, int ns,
                   const int* __restrict__ pcell, int* __restrict__ cursor,
                   float4* __restrict__ plist,
                   int nt, const int* __restrict__ tpcell,
                   int* __restrict__ tcursor, int* __restrict__ tsorted)
{
  int i = blockIdx.x * 256 + threadIdx.x;
  if (blockIdx.y == 0) {
    if (i >= ns) return;
    int slot = atomicAdd(&cursor[pcell[i]], 1);
    plist[slot] = make_float4(ps[3 * i], ps[3 * i + 1], ps[3 * i + 2],
                              __uint_as_float((unsigned)i));
  } else {
    if (i >= nt) return;
    int slot = atomicAdd(&tcursor[tpcell[i]], 1);
    tsorted[slot] = i;
  }
}

// ---------------------------------------------------------------------------
// L2 KNN search, quad-per-target. Exact u64 keys; certify at r=1,2 via
// cube-face lower bound; unresolved -> overflow (exact brute).
// ---------------------------------------------------------------------------
__global__ __launch_bounds__(256)
void knn_search_quad(const float* __restrict__ pos_t, int Nt,
                     const int* __restrict__ cellstart,
                     const float4* __restrict__ plist,
                     const int* __restrict__ tsorted,
                     float* __restrict__ widx,
                     int* __restrict__ ovf_cnt, int* __restrict__ ovf)
{
  int gid = blockIdx.x * 64 + (threadIdx.x >> 2);   // 64 targets per block
  int sub = threadIdx.x & 3;
  if (gid >= Nt) return;
  int t = tsorted[gid];
  float tx = pos_t[3 * t], ty = pos_t[3 * t + 1], tz = pos_t[3 * t + 2];
  int cx = cell_coord(tx), cy = cell_coord(ty), cz = cell_coord(tz);

  u64 k0 = ~0ULL, k1 = ~0ULL, k2 = ~0ULL;

  auto scan_range = [&](int p0, int p1, u64& a0, u64& a1, u64& a2) {
    for (int p = p0; p < p1; ++p) {
      float4 s = plist[p];
      float dx = tx - s.x, dy = ty - s.y, dz = tz - s.z;
      float d = fmaf(dz, dz, fmaf(dy, dy, dx * dx));
      key_insert(((u64)__float_as_uint(d) << 32) | (u64)__float_as_uint(s.w),
                 a0, a1, a2);
    }
  };

  auto certify = [&](int R) -> bool {
    int xl = max(cx - R, 0), xh = min(cx + R, GRD - 1);
    int yl = max(cy - R, 0), yh = min(cy + R, GRD - 1);
    int zl = max(cz - R, 0), zh = min(cz + R, GRD - 1);
    float m = 1e30f;
    if (xl > 0)       m = fminf(m, tx - (GLO + xl * GH));
    if (xh < GRD - 1) m = fminf(m, (GLO + (xh + 1) * GH) - tx);
    if (yl > 0)       m = fminf(m, ty - (GLO + yl * GH));
    if (yh < GRD - 1) m = fminf(m, (GLO + (yh + 1) * GH) - ty);
    if (zl > 0)       m = fminf(m, tz - (GLO + zl * GH));
    if (zh < GRD - 1) m = fminf(m, (GLO + (zh + 1) * GH) - tz);
    float d2b = __uint_as_float((unsigned)(k2 >> 32));   // NaN if <3 found
    return (m * m * 0.9999f > d2b);                      // NaN -> false
  };

  // Phase 1: 9 rows split across the quad
  int xlo = max(cx - 1, 0), xhi = min(cx + 1, GRD - 1);
  for (int id = sub; id < 9; id += 4) {
    int y = cy + (id % 3) - 1, z = cz + (id / 3) - 1;
    if (((unsigned)y < GRD) && ((unsigned)z < GRD)) {
      int base = (z * GRD + y) * GRD;
      scan_range(cellstart[base + xlo], cellstart[base + xhi + 1], k0, k1, k2);
    }
  }
  quad_merge(k0, k1, k2);
  bool done = certify(1);

  if (!done) {
    // Phase 2: r=2 shell (fresh disjoint keys -> butterfly -> cross merge)
    static const signed char o_dy[16] = {-2,-1,0,1,2, -2,-1,0,1,2, -2,-2,-2, 2,2,2};
    static const signed char o_dz[16] = {-2,-2,-2,-2,-2, 2,2,2,2,2, -1,0,1, -1,0,1};
    int xl2 = max(cx - 2, 0), xh2 = min(cx + 2, GRD - 1);
    u64 p0 = ~0ULL, p1 = ~0ULL, p2 = ~0ULL;
    for (int id = sub; id < 34; id += 4) {
      if (id < 16) {
        int y = cy + o_dy[id], z = cz + o_dz[id];
        if (((unsigned)y < GRD) && ((unsigned)z < GRD)) {
          int base = (z * GRD + y) * GRD;
          scan_range(cellstart[base + xl2], cellstart[base + xh2 + 1], p0, p1, p2);
        }
      } else {
        int row = (id - 16) >> 1, side = (id - 16) & 1;
        int y = cy + (row % 3) - 1, z = cz + (row / 3) - 1;
        int x = side ? (cx + 2) : (cx - 2);
        if (((unsigned)y < GRD) && ((unsigned)z < GRD) && ((unsigned)x < GRD)) {
          int base = (z * GRD + y) * GRD;
          scan_range(cellstart[base + x], cellstart[base + x + 1], p0, p1, p2);
        }
      }
    }
    quad_merge(p0, p1, p2);
    key_insert(p0, k0, k1, k2);
    key_insert(p1, k0, k1, k2);
    key_insert(p2, k0, k1, k2);
    done = certify(2);
  }

  if (!done) {
    if (sub == 0) ovf[atomicAdd(ovf_cnt, 1)] = t;
    return;
  }
  if (sub == 0) write_widx(widx, t, k0, k1, k2);
}

// ---------------------------------------------------------------------------
// Brute fallback: 4 targets/block, LDS-tiled sources, wave-tree shfl merge.
// ---------------------------------------------------------------------------
__global__ __launch_bounds__(256)
void knn_brute(const float* __restrict__ pos_t, const float4* __restrict__ plist,
               int Ns, const int* __restrict__ ovf_cnt,
               const int* __restrict__ ovf, float* __restrict__ widx)
{
  __shared__ float4 tile[1024];
  int n = *ovf_cnt;
  int ngrp = (n + 3) >> 2;
  int wv = threadIdx.x >> 6, ln = threadIdx.x & 63;

  for (int g = blockIdx.x; g < ngrp; g += gridDim.x) {
    int o = g * 4 + wv;
    bool active = (o < n);
    int t = active ? ovf[o] : 0;
    float tx = pos_t[3 * t], ty = pos_t[3 * t + 1], tz = pos_t[3 * t + 2];
    u64 k0 = ~0ULL, k1 = ~0ULL, k2 = ~0ULL;

    for (int base = 0; base < Ns; base += 1024) {
      int m = min(1024, Ns - base);
      __syncthreads();
      for (int i = threadIdx.x; i < m; i += 256) tile[i] = plist[base + i];
      __syncthreads();
#pragma unroll 4
      for (int p = ln; p < m; p += 64) {
        float4 s = tile[p];
        float dx = tx - s.x, dy = ty - s.y, dz = tz - s.z;
        float d = fmaf(dz, dz, fmaf(dy, dy, dx * dx));
        key_insert(((u64)__float_as_uint(d) << 32) | (u64)__float_as_uint(s.w),
                   k0, k1, k2);
      }
    }

#pragma unroll
    for (int off = 32; off >= 1; off >>= 1) {
      u64 a0 = __shfl_down(k0, off);
      u64 a1 = __shfl_down(k1, off);
      u64 a2 = __shfl_down(k2, off);
      key_insert(a0, k0, k1, k2);
      key_insert(a1, k0, k1, k2);
      key_insert(a2, k0, k1, k2);
    }
    if (active && ln == 0) write_widx(widx, t, k0, k1, k2);
  }
}

// ---------------------------------------------------------------------------
// fp32 tiled GEMM v4: Z[m][n] = sum_k A[m][k]*B[n][k] + bias[n].
// BOTH LDS tiles k-major with +4 pad: inner loop is 1x ds_read_b128 (B) +
// 1x ds_read_b64/b128 (A) per k for AR*4 FMAs (73-84% FMA issue share).
// Staging: 4 scalar scatter-writes per loaded float4 (4-way bank aliasing,
// amortized over the 32-step compute loop). Register prefetch overlaps the
// next tile's global loads (incl. the fused knn gather) with the FMA loop.
// CONCAT: A = [A0 (C0 cols) | interp(xs, widx)]; BNIN: A = relu(bn(A0)).
// ---------------------------------------------------------------------------
template<int BM, int BN, int CONCAT, int BNIN>
__global__ __launch_bounds__(256, 4)
void gemm_k(const float* __restrict__ A0, const float* __restrict__ xs,
            const float* __restrict__ wvec, int C0, int ldx,
            const float* __restrict__ B, const float* __restrict__ bias,
            const float* __restrict__ s_in, const float* __restrict__ q_in,
            const float* __restrict__ g_in, const float* __restrict__ be_in,
            float* __restrict__ Z, float* __restrict__ s_out, float* __restrict__ q_out,
            int M, int K, int N)
{
  constexpr int BK = 32;
  constexpr int TN = BN / 4;          // column-group threads
  constexpr int TM = 256 / TN;        // row threads
  constexpr int AR = BM / TM;         // rows per thread (2 or 4)
  constexpr int NA = BM / 32;         // A float4 loads per thread
  constexpr int NB = BN / 32;         // B float4 loads per thread

  __shared__ alignas(16) float a_lds[BK][BM + 4];   // k-major
  __shared__ alignas(16) float b_lds[BK][BN + 4];   // k-major
  __shared__ float bn_sc[256], bn_sh[256];

  const int tid = threadIdx.x;
  const int tn = tid % TN, tm = tid / TN;
  const int mb = blockIdx.x * BM;
  const int nb = blockIdx.y * BN;

  if (BNIN) {
    for (int c = tid; c < K; c += 256) {
      float mean = s_in[c] / (float)M;
      float var  = q_in[c] / (float)M - mean * mean;
      float rstd = rsqrtf(var + EPS_BN);
      float sc = g_in[c] * rstd;
      bn_sc[c] = sc;
      bn_sh[c] = be_in[c] - mean * sc;
    }
    __syncthreads();
  }

  float acc[AR][4];
#pragma unroll
  for (int i = 0; i < AR; ++i)
#pragma unroll
    for (int j = 0; j < 4; ++j) acc[i][j] = 0.f;

  float4 pa[NA], pb[NB];

  auto prefetch = [&](int kb) {
    if (CONCAT && kb >= C0) {
      int ko = kb - C0;
#pragma unroll
      for (int i = 0; i < NA; ++i) {
        int sl = tid + 256 * i;
        int m = sl >> 3, k4 = (sl & 7) * 4;
        int t = mb + m;
        float4 wvv = *(const float4*)&wvec[(size_t)t * 8];
        float4 ivv = *(const float4*)&wvec[(size_t)t * 8 + 4];
        const float4 r0 = *(const float4*)(xs + (size_t)__float_as_uint(ivv.x) * ldx + ko + k4);
        const float4 r1 = *(const float4*)(xs + (size_t)__float_as_uint(ivv.y) * ldx + ko + k4);
        const float4 r2 = *(const float4*)(xs + (size_t)__float_as_uint(ivv.z) * ldx + ko + k4);
        pa[i].x = wvv.x * r0.x + wvv.y * r1.x + wvv.z * r2.x;
        pa[i].y = wvv.x * r0.y + wvv.y * r1.y + wvv.z * r2.y;
        pa[i].z = wvv.x * r0.z + wvv.y * r1.z + wvv.z * r2.z;
        pa[i].w = wvv.x * r0.w + wvv.y * r1.w + wvv.z * r2.w;
      }
    } else {
      int ldA = CONCAT ? C0 : K;
#pragma unroll
      for (int i = 0; i < NA; ++i) {
        int sl = tid + 256 * i;
        int m = sl >> 3, k4 = (sl & 7) * 4;
        pa[i] = *(const float4*)(A0 + (size_t)(mb + m) * ldA + kb + k4);
      }
    }
#pragma unroll
    for (int i = 0; i < NB; ++i) {
      int sl = tid + 256 * i;
      int nn = sl >> 3, k4 = (sl & 7) * 4;
      pb[i] = *(const float4*)(B + (size_t)(nb + nn) * K + kb + k4);
    }
  };

  prefetch(0);

  for (int kb = 0; kb < K; kb += BK) {
    // commit staged registers to LDS (k-major scatter)
#pragma unroll
    for (int i = 0; i < NA; ++i) {
      int sl = tid + 256 * i;
      int m = sl >> 3, k4 = (sl & 7) * 4;
      float4 v = pa[i];
      if (BNIN) {
        v.x = fmaxf(v.x * bn_sc[kb + k4 + 0] + bn_sh[kb + k4 + 0], 0.f);
        v.y = fmaxf(v.y * bn_sc[kb + k4 + 1] + bn_sh[kb + k4 + 1], 0.f);
        v.z = fmaxf(v.z * bn_sc[kb + k4 + 2] + bn_sh[kb + k4 + 2], 0.f);
        v.w = fmaxf(v.w * bn_sc[kb + k4 + 3] + bn_sh[kb + k4 + 3], 0.f);
      }
      a_lds[k4 + 0][m] = v.x; a_lds[k4 + 1][m] = v.y;
      a_lds[k4 + 2][m] = v.z; a_lds[k4 + 3][m] = v.w;
    }
#pragma unroll
    for (int i = 0; i < NB; ++i) {
      int sl = tid + 256 * i;
      int nn = sl >> 3, k4 = (sl & 7) * 4;
      float4 v = pb[i];
      b_lds[k4 + 0][nn] = v.x; b_lds[k4 + 1][nn] = v.y;
      b_lds[k4 + 2][nn] = v.z; b_lds[k4 + 3][nn] = v.w;
    }
    __syncthreads();
    if (kb + BK < K) prefetch(kb + BK);   // overlaps with FMA loop

#pragma unroll
    for (int k = 0; k < BK; ++k) {
      float4 bv = *(const float4*)&b_lds[k][tn * 4];
      float av[AR];
      if constexpr (AR == 2) {
        float2 t2 = *(const float2*)&a_lds[k][tm * 2];
        av[0] = t2.x; av[1] = t2.y;
      } else {
        float4 t4 = *(const float4*)&a_lds[k][tm * 4];
        av[0] = t4.x; av[1] = t4.y; av[2] = t4.z; av[3] = t4.w;
      }
#pragma unroll
      for (int i = 0; i < AR; ++i) {
        acc[i][0] = fmaf(av[i], bv.x, acc[i][0]);
        acc[i][1] = fmaf(av[i], bv.y, acc[i][1]);
        acc[i][2] = fmaf(av[i], bv.z, acc[i][2]);
        acc[i][3] = fmaf(av[i], bv.w, acc[i][3]);
      }
    }
    __syncthreads();
  }

  // epilogue: bias add, store, per-column partial stats
  float4 bb = *(const float4*)&bias[nb + tn * 4];
  float psum[4] = {0, 0, 0, 0}, psq[4] = {0, 0, 0, 0};
#pragma unroll
  for (int i = 0; i < AR; ++i) {
    int m = tm * AR + i;
    float4 v;
    v.x = acc[i][0] + bb.x; v.y = acc[i][1] + bb.y;
    v.z = acc[i][2] + bb.z; v.w = acc[i][3] + bb.w;
    *(float4*)(Z + (size_t)(mb + m) * N + nb + tn * 4) = v;
    psum[0] += v.x; psum[1] += v.y; psum[2] += v.z; psum[3] += v.w;
    psq[0] += v.x * v.x; psq[1] += v.y * v.y;
    psq[2] += v.z * v.z; psq[3] += v.w * v.w;
  }
  __syncthreads();
  float* red_s = &b_lds[0][0];   // BK*(BN+4) >= BN*TM
  float* red_q = &a_lds[0][0];   // BK*(BM+4) >= BN*TM
#pragma unroll
  for (int j = 0; j < 4; ++j) {
    int c = tn * 4 + j;
    red_s[c * TM + tm] = psum[j];
    red_q[c * TM + tm] = psq[j];
  }
  __syncthreads();
  if (tid < BN) {
    float s = 0.f, q = 0.f;
#pragma unroll
    for (int it = 0; it < TM; ++it) {
      s += red_s[tid * TM + it];
      q += red_q[tid * TM + it];
    }
    atomicAdd(&s_out[nb + tid], s);
    atomicAdd(&q_out[nb + tid], q);
  }
}

// ---------------------------------------------------------------------------
// Final elementwise per level: out = relu(bn1(z1)) + relu(bn2(z2)).
// Optional tail: zero `zbuf[0..zn)` (used by L1 to clear L2's grid counters).
// ---------------------------------------------------------------------------
__global__ __launch_bounds__(256)
void final_k(const float* __restrict__ z1, const float* __restrict__ z2,
             const float* __restrict__ s1, const float* __restrict__ q1,
             const float* __restrict__ g1, const float* __restrict__ be1,
             const float* __restrict__ s2, const float* __restrict__ q2,
             const float* __restrict__ g2, const float* __restrict__ be2,
             float* __restrict__ outp, int M, int C,
             int* __restrict__ zbuf, int zn)
{
  __shared__ float sc1[256], sh1[256], sc2[256], sh2[256];
  for (int c = threadIdx.x; c < C; c += 256) {
    float mean = s1[c] / (float)M;
    float var  = q1[c] / (float)M - mean * mean;
    float r = rsqrtf(var + EPS_BN);
    sc1[c] = g1[c] * r; sh1[c] = be1[c] - mean * sc1[c];
    mean = s2[c] / (float)M;
    var  = q2[c] / (float)M - mean * mean;
    r = rsqrtf(var + EPS_BN);
    sc2[c] = g2[c] * r; sh2[c] = be2[c] - mean * sc2[c];
  }
  __syncthreads();

  if (zbuf) {
    int gtid = blockIdx.x * 256 + threadIdx.x;
    for (int i = gtid; i < zn; i += gridDim.x * 256) zbuf[i] = 0;
  }

  int total4 = M * C / 4;
  int cmask = (C / 4) - 1;                   // C/4 is a power of two
  for (int i = blockIdx.x * 256 + threadIdx.x; i < total4; i += gridDim.x * 256) {
    int c = (i & cmask) * 4;
    float4 a = ((const float4*)z1)[i];
    float4 b = ((const float4*)z2)[i];
    float4 r;
    r.x = fmaxf(a.x * sc1[c + 0] + sh1[c + 0], 0.f) + fmaxf(b.x * sc2[c + 0] + sh2[c + 0], 0.f);
    r.y = fmaxf(a.y * sc1[c + 1] + sh1[c + 1], 0.f) + fmaxf(b.y * sc2[c + 1] + sh2[c + 1], 0.f);
    r.z = fmaxf(a.z * sc1[c + 2] + sh1[c + 2], 0.f) + fmaxf(b.z * sc2[c + 2] + sh2[c + 2], 0.f);
    r.w = fmaxf(a.w * sc1[c + 3] + sh1[c + 3], 0.f) + fmaxf(b.w * sc2[c + 3] + sh2[c + 3], 0.f);
    ((float4*)outp)[i] = r;
  }
}

// ---------------------------------------------------------------------------
extern "C" void kernel_launch(void* const* d_in, const int* in_sizes, int n_in,
                              void* d_out, int out_size, void* d_ws, size_t ws_size,
                              hipStream_t stream)
{
  const bool dict_order = (in_sizes[1] == 512 * 512);

  const float* POS[4];
  const float* X[4];
  for (int i = 0; i < 4; ++i) {
    POS[i] = (const float*)d_in[dict_order ? 3 * i : i];
    X[i]   = (const float*)d_in[dict_order ? 3 * i + 1 : 4 + i];
  }
  static const int dict_map[8] = {0, 2, 6, 3, 1, 4, 7, 5};
  auto PRM = [&](int lvl, int which) -> const float* {
    int idx = dict_order ? (12 + 8 * lvl + dict_map[which]) : (8 + 8 * lvl + which);
    return (const float*)d_in[idx];
  };

  // Workspace layout (~31.2 MB, all regions disjoint; no `up` buffer):
  char* ws = (char*)d_ws;
  float* z1    = (float*)(ws);                          // 8 MB max
  float* z2    = (float*)(ws + (8u << 20));             // 8 MB max
  float* x1o   = (float*)(ws + (16u << 20));            // 2 MB
  float* x2o   = (float*)(ws + (18u << 20));            // 4 MB
  float* stats = (float*)(ws + (22u << 20));            // 4 KB (pad 8 KB)
  float* s1 = stats, *q1 = stats + 256, *s2 = stats + 512, *q2 = stats + 768;
  char*  wb   = ws + (22u << 20) + 8192;
  float* widx0 = (float*)(wb);                          // 64 KB
  float* widx1 = (float*)(wb + 65536);                  // 256 KB
  float* widx2 = (float*)(wb + 65536 + 262144);         // 1 MB

  char* gb = ws + (24u << 20);
  const size_t S = 600 * 1024;
  int*    ofsp     = (int*)(gb + 0 * S);
  int*    tofsp    = (int*)(gb + 1 * S);
  int*    cursor   = (int*)(gb + 2 * S);
  int*    tcursor  = (int*)(gb + 3 * S);
  int*    cellstart= (int*)(gb + 4 * S);                // NCELLS+1 ints
  char*   gb2      = gb + 5 * S;
  int*    aux      = (int*)(gb2);
  int*    aux2     = (int*)(gb2 + 1024);
  int*    pcell    = (int*)(gb2 + 4096);                        // 32 KB
  int*    tpcell   = (int*)(gb2 + 4096 + 32768);                // 128 KB
  float4* plist    = (float4*)(gb2 + 4096 + 32768 + 131072);    // 128 KB
  int*    tsorted  = (int*)(gb2 + 4096 + 32768 + 2 * 131072);   // 128 KB
  int*    ovfc     = (int*)(gb2 + 4096 + 32768 + 3 * 131072);
  int*    ovf      = (int*)(gb2 + 4096 + 32768 + 3 * 131072 + 1024); // 128 KB
  int*    cnt      = (int*)(ws + (30u << 20));          // S (zeroed by L1 final)
  int*    tcnt     = (int*)(ws + (30u << 20) + S);      // S

  // ======================= Level 0: 512 -> 2048 ============================
  knn_fused<2><<<32, 256, 0, stream>>>(POS[0], POS[1], 512, 2048, widx0, stats);
  gemm_k<32, 64, 1, 0><<<dim3(64, 4), 256, 0, stream>>>(
      X[1], X[0], widx0, 256, 512, PRM(0, 0), PRM(0, 1),
      nullptr, nullptr, nullptr, nullptr,
      z1, s1, q1, 2048, 768, 256);
  gemm_k<32, 64, 0, 1><<<dim3(64, 4), 256, 0, stream>>>(
      z1, nullptr, nullptr, 0, 0, PRM(0, 4), PRM(0, 5),
      s1, q1, PRM(0, 2), PRM(0, 3),
      z2, s2, q2, 2048, 256, 256);
  final_k<<<512, 256, 0, stream>>>(z1, z2, s1, q1, PRM(0, 2), PRM(0, 3),
                                   s2, q2, PRM(0, 6), PRM(0, 7), x1o, 2048, 256,
                                   nullptr, 0);

  // ======================= Level 1: 2048 -> 8192 ===========================
  knn_fused<3><<<256, 256, 0, stream>>>(POS[1], POS[2], 2048, 8192, widx1, stats);
  gemm_k<32, 64, 1, 0><<<dim3(256, 2), 256, 0, stream>>>(
      X[2], x1o, widx1, 128, 256, PRM(1, 0), PRM(1, 1),
      nullptr, nullptr, nullptr, nullptr,
      z1, s1, q1, 8192, 384, 128);
  gemm_k<32, 64, 0, 1><<<dim3(256, 2), 256, 0, stream>>>(
      z1, nullptr, nullptr, 0, 0, PRM(1, 4), PRM(1, 5),
      s1, q1, PRM(1, 2), PRM(1, 3),
      z2, s2, q2, 8192, 128, 128);
  final_k<<<1024, 256, 0, stream>>>(z1, z2, s1, q1, PRM(1, 2), PRM(1, 3),
                                    s2, q2, PRM(1, 6), PRM(1, 7), x2o, 8192, 128,
                                    cnt, (int)(2 * S / 4));   // zero cnt+tcnt

  // ======================= Level 2: 8192 -> 32768 (grid KNN) ===============
  grid_count2<<<dim3(128, 2), 256, 0, stream>>>(POS[2], 8192, cnt, pcell,
                                                POS[3], 32768, tcnt, tpcell);
  grid_scan1<<<dim3(138, 2), 256, 0, stream>>>(cnt, ofsp, aux, tcnt, tofsp, aux2);
  grid_fixup2<<<dim3(256, 2), 256, 0, stream>>>(ofsp, aux, cursor, cellstart, 8192,
                                                tofsp, aux2, tcursor, ovfc, stats);
  grid_scatter2<<<dim3(128, 2), 256, 0, stream>>>(POS[2], 8192, pcell, cursor, plist,
                                                  32768, tpcell, tcursor, tsorted);
  knn_search_quad<<<512, 256, 0, stream>>>(POS[3], 32768, cellstart, plist,
                                           tsorted, widx2, ovfc, ovf);
  knn_brute<<<256, 256, 0, stream>>>(POS[3], plist, 8192, ovfc, ovf, widx2);
  gemm_k<64, 64, 1, 0><<<dim3(512, 1), 256, 0, stream>>>(
      X[3], x2o, widx2, 64, 128, PRM(2, 0), PRM(2, 1),
      nullptr, nullptr, nullptr, nullptr,
      z1, s1, q1, 32768, 192, 64);
  gemm_k<64, 64, 0, 1><<<dim3(512, 1), 256, 0, stream>>>(
      z1, nullptr, nullptr, 0, 0, PRM(2, 4), PRM(2, 5),
      s1, q1, PRM(2, 2), PRM(2, 3),
      z2, s2, q2, 32768, 64, 64);
  final_k<<<1024, 256, 0, stream>>>(z1, z2, s1, q1, PRM(2, 2), PRM(2, 3),
                                    s2, q2, PRM(2, 6), PRM(2, 7),
                                    (float*)d_out, 32768, 64, nullptr, 0);
}